// Round 1
// baseline (2901.826 us; speedup 1.0000x reference)
//
#include <hip/hip_runtime.h>

#define N_NODES 100000
#define N_EDGES 1600000
#define DIM 128
#define NH 4
#define TILE_N 32
#define LDST 36  // padded LDS row stride (floats): 144B = 16B-aligned rows, conflict-free staging

// ---------------------------------------------------------------------------
// Average the per-head weights: mean over heads commutes with the einsum+mean.
// wavg layout: [ Wsavg 128*128 | Wnavg 128*128 | bavg 128 ]
// ---------------------------------------------------------------------------
__global__ void avg_weights_kernel(const float* __restrict__ Ws,
                                   const float* __restrict__ Wn,
                                   const float* __restrict__ b,
                                   float* __restrict__ wavg) {
    int i = blockIdx.x * 256 + threadIdx.x;
    if (i < DIM * DIM) {
        float s = 0.f, n = 0.f;
#pragma unroll
        for (int hh = 0; hh < NH; ++hh) {
            s += Ws[hh * DIM * DIM + i];
            n += Wn[hh * DIM * DIM + i];
        }
        wavg[i] = 0.25f * s;
        wavg[DIM * DIM + i] = 0.25f * n;
    }
    if (i < DIM) {
        float bb = 0.f;
#pragma unroll
        for (int hh = 0; hh < NH; ++hh) bb += b[hh * DIM + i];
        wavg[2 * DIM * DIM + i] = 0.25f * bb;
    }
}

// ---------------------------------------------------------------------------
// Edge scatter: nsum[dst] += h[src] (f32 atomics), deg[dst] += 1.
// 32 lanes per edge, float4 per lane -> 4 atomics per lane.
// ---------------------------------------------------------------------------
__global__ __launch_bounds__(256) void scatter_kernel(
    const float* __restrict__ h, const int* __restrict__ src,
    const int* __restrict__ dst, float* __restrict__ nsum,
    float* __restrict__ deg) {
    int e = blockIdx.x * 8 + (threadIdx.x >> 5);
    int lane = threadIdx.x & 31;
    int s = src[e];
    int d = dst[e];
    float4 v = reinterpret_cast<const float4*>(h + (size_t)s * DIM)[lane];
    float* base = nsum + (size_t)d * DIM + lane * 4;
    atomicAdd(base + 0, v.x);
    atomicAdd(base + 1, v.y);
    atomicAdd(base + 2, v.z);
    atomicAdd(base + 3, v.w);
    if (lane == 0) atomicAdd(deg + d, 1.0f);
}

// ---------------------------------------------------------------------------
// Fused GEMM: out[n] = h[n]@Ws + (nsum[n]/max(deg,1))@Wn + bavg
// nsum lives in `out` and is overwritten in place (row-local dependency).
// Block: 256 threads, 32-node tile. Thread = 4 nodes x 4 outs micro-tile.
// h/ns staged transposed [d][n] in LDS -> ds_read_b128 along n.
// ---------------------------------------------------------------------------
__global__ __launch_bounds__(256) void fused_gemm_kernel(
    const float* __restrict__ h, float* __restrict__ out,
    const float* __restrict__ deg, const float* __restrict__ wavg) {
    __shared__ float hsT[DIM][LDST];
    __shared__ float nsT[DIM][LDST];
    const float* Ws = wavg;
    const float* Wn = wavg + DIM * DIM;
    const float* bavg = wavg + 2 * DIM * DIM;
    const int tile = blockIdx.x * TILE_N;
    const int tid = threadIdx.x;

    // Stage 32 rows of h and nsum (transposed). Lanes: n = i&31 -> LDS banks
    // (16c+4j+n)%32 cover all 32 -> conflict-free; global reads are 16B/lane
    // row-gathers that fully cover cache lines across the loop (L2/L3-hot).
    for (int i = tid; i < TILE_N * (DIM / 4); i += 256) {
        int n = i & 31;
        int c = i >> 5;
        size_t row = (size_t)(tile + n) * DIM;
        float4 hv = reinterpret_cast<const float4*>(h + row)[c];
        float4 nv = reinterpret_cast<const float4*>(out + row)[c];
        int d0 = c * 4;
        hsT[d0 + 0][n] = hv.x; hsT[d0 + 1][n] = hv.y;
        hsT[d0 + 2][n] = hv.z; hsT[d0 + 3][n] = hv.w;
        nsT[d0 + 0][n] = nv.x; nsT[d0 + 1][n] = nv.y;
        nsT[d0 + 2][n] = nv.z; nsT[d0 + 3][n] = nv.w;
    }
    __syncthreads();

    const int og = tid & 31;  const int o0 = og * 4;
    const int ng = tid >> 5;  const int n0 = ng * 4;

    float accS[4][4] = {{0.f}};
    float accN[4][4] = {{0.f}};

    for (int d = 0; d < DIM; ++d) {
        float4 a  = *reinterpret_cast<const float4*>(&hsT[d][n0]);
        float4 an = *reinterpret_cast<const float4*>(&nsT[d][n0]);
        float4 ws = reinterpret_cast<const float4*>(Ws + d * DIM)[og];
        float4 wn = reinterpret_cast<const float4*>(Wn + d * DIM)[og];
        float av[4]  = {a.x, a.y, a.z, a.w};
        float nv[4]  = {an.x, an.y, an.z, an.w};
        float wsv[4] = {ws.x, ws.y, ws.z, ws.w};
        float wnv[4] = {wn.x, wn.y, wn.z, wn.w};
#pragma unroll
        for (int i = 0; i < 4; ++i)
#pragma unroll
            for (int j = 0; j < 4; ++j) {
                accS[i][j] = fmaf(av[i], wsv[j], accS[i][j]);
                accN[i][j] = fmaf(nv[i], wnv[j], accN[i][j]);
            }
    }

    float4 bb = reinterpret_cast<const float4*>(bavg)[og];
    float bv[4] = {bb.x, bb.y, bb.z, bb.w};
#pragma unroll
    for (int i = 0; i < 4; ++i) {
        int node = tile + n0 + i;
        float invd = 1.0f / fmaxf(deg[node], 1.0f);
        float4 r;
        r.x = fmaf(accN[i][0], invd, accS[i][0]) + bv[0];
        r.y = fmaf(accN[i][1], invd, accS[i][1]) + bv[1];
        r.z = fmaf(accN[i][2], invd, accS[i][2]) + bv[2];
        r.w = fmaf(accN[i][3], invd, accS[i][3]) + bv[3];
        reinterpret_cast<float4*>(out + (size_t)node * DIM)[og] = r;
    }
    (void)o0;
}

extern "C" void kernel_launch(void* const* d_in, const int* in_sizes, int n_in,
                              void* d_out, int out_size, void* d_ws, size_t ws_size,
                              hipStream_t stream) {
    const float* h  = (const float*)d_in[0];
    const int* src  = (const int*)d_in[1];
    const int* dst  = (const int*)d_in[2];
    const float* Ws = (const float*)d_in[3];
    const float* Wn = (const float*)d_in[4];
    const float* b  = (const float*)d_in[5];
    float* out = (float*)d_out;

    float* deg  = (float*)d_ws;            // N_NODES floats
    float* wavg = (float*)d_ws + N_NODES;  // 2*128*128 + 128 floats (16B-aligned offset)

    hipMemsetAsync(d_out, 0, (size_t)N_NODES * DIM * sizeof(float), stream);
    hipMemsetAsync(deg, 0, N_NODES * sizeof(float), stream);

    avg_weights_kernel<<<(DIM * DIM + 255) / 256, 256, 0, stream>>>(Ws, Wn, b, wavg);
    scatter_kernel<<<N_EDGES / 8, 256, 0, stream>>>(h, src, dst, out, deg);
    fused_gemm_kernel<<<N_NODES / TILE_N, 256, 0, stream>>>(h, out, deg, wavg);
}

// Round 2
// 607.345 us; speedup vs baseline: 4.7779x; 4.7779x over previous
//
#include <hip/hip_runtime.h>

#define N_NODES 100000
#define N_EDGES 1600000
#define DIM 128
#define NH 4
#define TILE_N 32
#define LDST 36  // padded LDS row stride (floats)

// ws layout (ints unless noted):
//   rowoff : [0, 100352)              exclusive scan of deg, +1 slot for total
//   cursor : [100352, 200704)         histogram counts, then fill cursors
//   csr    : [200704, 1800704)        src node id per edge, bucketed by dst
//   wavg   : float[1800704 .. +32896) averaged Ws|Wn|b
#define OFF_ROWOFF 0
#define OFF_CURSOR 100352
#define OFF_CSR    200704
#define OFF_WAVG   1800704

// ---------------------------------------------------------------------------
// mean over heads commutes with einsum+mean -> pre-average weights (4x FLOPs cut)
// ---------------------------------------------------------------------------
__global__ void avg_weights_kernel(const float* __restrict__ Ws,
                                   const float* __restrict__ Wn,
                                   const float* __restrict__ b,
                                   float* __restrict__ wavg) {
    int i = blockIdx.x * 256 + threadIdx.x;
    if (i < DIM * DIM) {
        float s = 0.f, n = 0.f;
#pragma unroll
        for (int hh = 0; hh < NH; ++hh) {
            s += Ws[hh * DIM * DIM + i];
            n += Wn[hh * DIM * DIM + i];
        }
        wavg[i] = 0.25f * s;
        wavg[DIM * DIM + i] = 0.25f * n;
    }
    if (i < DIM) {
        float bb = 0.f;
#pragma unroll
        for (int hh = 0; hh < NH; ++hh) bb += b[hh * DIM + i];
        wavg[2 * DIM * DIM + i] = 0.25f * bb;
    }
}

// ---------------------------------------------------------------------------
// 1) degree histogram (int atomics into L2-resident 400KB array)
// ---------------------------------------------------------------------------
__global__ __launch_bounds__(256) void deg_hist_kernel(const int* __restrict__ dst,
                                                       int* __restrict__ cnt) {
    int e = blockIdx.x * 256 + threadIdx.x;
    atomicAdd(&cnt[dst[e]], 1);
}

// ---------------------------------------------------------------------------
// 2) single-workgroup exclusive scan of 100K counts -> rowoff; zeroes cnt.
// ---------------------------------------------------------------------------
__global__ __launch_bounds__(1024) void scan_kernel(int* __restrict__ cnt,
                                                    int* __restrict__ rowoff) {
    __shared__ int sums[1024];
    const int T = 1024;
    const int CH = (N_NODES + T - 1) / T;  // 98
    int t = threadIdx.x;
    int lo = t * CH;
    int hi = min(lo + CH, N_NODES);
    int s = 0;
    for (int i = lo; i < hi; ++i) s += cnt[i];
    sums[t] = s;
    __syncthreads();
    for (int off = 1; off < T; off <<= 1) {
        int add = (t >= off) ? sums[t - off] : 0;
        __syncthreads();
        sums[t] += add;
        __syncthreads();
    }
    int excl = (t == 0) ? 0 : sums[t - 1];
    for (int i = lo; i < hi; ++i) {
        int c = cnt[i];
        rowoff[i] = excl;
        excl += c;
        cnt[i] = 0;  // becomes the fill cursor
    }
    if (t == T - 1) rowoff[N_NODES] = excl;
}

// ---------------------------------------------------------------------------
// 3) bucket edges by dst: csr[rowoff[d] + cursor[d]++] = src
// ---------------------------------------------------------------------------
__global__ __launch_bounds__(256) void fill_csr_kernel(const int* __restrict__ src,
                                                       const int* __restrict__ dst,
                                                       const int* __restrict__ rowoff,
                                                       int* __restrict__ cursor,
                                                       int* __restrict__ csr) {
    int e = blockIdx.x * 256 + threadIdx.x;
    int d = dst[e];
    int pos = rowoff[d] + atomicAdd(&cursor[d], 1);
    csr[pos] = src[e];
}

// ---------------------------------------------------------------------------
// 4) gather-mean: one 64-lane wave per node, float2 per lane (512B/row/wave).
//    csr index is wave-uniform -> scalar loads. out = sum(h[src]) / max(deg,1).
// ---------------------------------------------------------------------------
__global__ __launch_bounds__(256) void gather_mean_kernel(const float* __restrict__ h,
                                                          const int* __restrict__ rowoff,
                                                          const int* __restrict__ csr,
                                                          float* __restrict__ out) {
    int node = blockIdx.x * 4 + (threadIdx.x >> 6);
    int lane = threadIdx.x & 63;
    int lo = rowoff[node];
    int hi = rowoff[node + 1];
    const float2* h2 = reinterpret_cast<const float2*>(h);
    float ax = 0.f, ay = 0.f;
    int k = lo;
    for (; k + 3 < hi; k += 4) {  // unroll-4: 4 independent loads in flight
        int s0 = csr[k], s1 = csr[k + 1], s2 = csr[k + 2], s3 = csr[k + 3];
        float2 v0 = h2[(size_t)s0 * 64 + lane];
        float2 v1 = h2[(size_t)s1 * 64 + lane];
        float2 v2 = h2[(size_t)s2 * 64 + lane];
        float2 v3 = h2[(size_t)s3 * 64 + lane];
        ax += v0.x + v1.x + v2.x + v3.x;
        ay += v0.y + v1.y + v2.y + v3.y;
    }
    for (; k < hi; ++k) {
        int s0 = csr[k];
        float2 v0 = h2[(size_t)s0 * 64 + lane];
        ax += v0.x;
        ay += v0.y;
    }
    float inv = 1.0f / (float)max(hi - lo, 1);
    reinterpret_cast<float2*>(out)[(size_t)node * 64 + lane] = make_float2(ax * inv, ay * inv);
}

// ---------------------------------------------------------------------------
// 5) fused GEMM: out[n] = h[n]@Ws + hn[n]@Wn + bavg   (hn lives in `out`,
//    overwritten in place; row-local dependency).
// ---------------------------------------------------------------------------
__global__ __launch_bounds__(256) void fused_gemm_kernel(const float* __restrict__ h,
                                                         float* __restrict__ out,
                                                         const float* __restrict__ wavg) {
    __shared__ float hsT[DIM][LDST];
    __shared__ float nsT[DIM][LDST];
    const float* Ws = wavg;
    const float* Wn = wavg + DIM * DIM;
    const float* bavg = wavg + 2 * DIM * DIM;
    const int tile = blockIdx.x * TILE_N;
    const int tid = threadIdx.x;

    for (int i = tid; i < TILE_N * (DIM / 4); i += 256) {
        int n = i & 31;
        int c = i >> 5;
        size_t row = (size_t)(tile + n) * DIM;
        float4 hv = reinterpret_cast<const float4*>(h + row)[c];
        float4 nv = reinterpret_cast<const float4*>(out + row)[c];
        int d0 = c * 4;
        hsT[d0 + 0][n] = hv.x; hsT[d0 + 1][n] = hv.y;
        hsT[d0 + 2][n] = hv.z; hsT[d0 + 3][n] = hv.w;
        nsT[d0 + 0][n] = nv.x; nsT[d0 + 1][n] = nv.y;
        nsT[d0 + 2][n] = nv.z; nsT[d0 + 3][n] = nv.w;
    }
    __syncthreads();

    const int og = tid & 31;
    const int ng = tid >> 5;
    const int n0 = ng * 4;

    float accS[4][4] = {{0.f}};
    float accN[4][4] = {{0.f}};

    for (int d = 0; d < DIM; ++d) {
        float4 a  = *reinterpret_cast<const float4*>(&hsT[d][n0]);
        float4 an = *reinterpret_cast<const float4*>(&nsT[d][n0]);
        float4 ws = reinterpret_cast<const float4*>(Ws + d * DIM)[og];
        float4 wn = reinterpret_cast<const float4*>(Wn + d * DIM)[og];
        float av[4]  = {a.x, a.y, a.z, a.w};
        float nv[4]  = {an.x, an.y, an.z, an.w};
        float wsv[4] = {ws.x, ws.y, ws.z, ws.w};
        float wnv[4] = {wn.x, wn.y, wn.z, wn.w};
#pragma unroll
        for (int i = 0; i < 4; ++i)
#pragma unroll
            for (int j = 0; j < 4; ++j) {
                accS[i][j] = fmaf(av[i], wsv[j], accS[i][j]);
                accN[i][j] = fmaf(nv[i], wnv[j], accN[i][j]);
            }
    }

    float4 bb = reinterpret_cast<const float4*>(bavg)[og];
    float bv[4] = {bb.x, bb.y, bb.z, bb.w};
#pragma unroll
    for (int i = 0; i < 4; ++i) {
        int node = tile + n0 + i;
        float4 r;
        r.x = accS[i][0] + accN[i][0] + bv[0];
        r.y = accS[i][1] + accN[i][1] + bv[1];
        r.z = accS[i][2] + accN[i][2] + bv[2];
        r.w = accS[i][3] + accN[i][3] + bv[3];
        reinterpret_cast<float4*>(out + (size_t)node * DIM)[og] = r;
    }
}

extern "C" void kernel_launch(void* const* d_in, const int* in_sizes, int n_in,
                              void* d_out, int out_size, void* d_ws, size_t ws_size,
                              hipStream_t stream) {
    const float* h  = (const float*)d_in[0];
    const int* src  = (const int*)d_in[1];
    const int* dst  = (const int*)d_in[2];
    const float* Ws = (const float*)d_in[3];
    const float* Wn = (const float*)d_in[4];
    const float* b  = (const float*)d_in[5];
    float* out = (float*)d_out;

    int* wsi    = (int*)d_ws;
    int* rowoff = wsi + OFF_ROWOFF;
    int* cursor = wsi + OFF_CURSOR;
    int* csr    = wsi + OFF_CSR;
    float* wavg = (float*)d_ws + OFF_WAVG;

    hipMemsetAsync(cursor, 0, N_NODES * sizeof(int), stream);

    avg_weights_kernel<<<(DIM * DIM + 255) / 256, 256, 0, stream>>>(Ws, Wn, b, wavg);
    deg_hist_kernel<<<N_EDGES / 256, 256, 0, stream>>>(dst, cursor);
    scan_kernel<<<1, 1024, 0, stream>>>(cursor, rowoff);
    fill_csr_kernel<<<N_EDGES / 256, 256, 0, stream>>>(src, dst, rowoff, cursor, csr);
    gather_mean_kernel<<<N_NODES / 4, 256, 0, stream>>>(h, rowoff, csr, out);
    fused_gemm_kernel<<<N_NODES / TILE_N, 256, 0, stream>>>(h, out, wavg);
}

// Round 3
// 416.690 us; speedup vs baseline: 6.9640x; 1.4575x over previous
//
#include <hip/hip_runtime.h>

#define N_NODES 100000
#define N_EDGES 1600000
#define DIM 128
#define NH 4
#define TILE_N 32
#define LDST 36  // padded LDS row stride (floats)

#define SCAN_BLK 1024
#define SCAN_NB ((N_NODES + SCAN_BLK - 1) / SCAN_BLK)  // 98

// ws layout (int32 indices unless noted):
//   rowoff : [0, 100352)              exclusive scan of deg, +1 slot for total
//   cursor : [100352, 200704)         histogram counts, then fill cursors
//   blksum : [200704, 200832)         per-block scan totals (128 slots)
//   csr    : [200832, 1800832)        src node id per edge, bucketed by dst
//   wavg   : float[1800832 .. +32896) averaged Ws|Wn|b
#define OFF_ROWOFF 0
#define OFF_CURSOR 100352
#define OFF_BLKSUM 200704
#define OFF_CSR    200832
#define OFF_WAVG   1800832

// ---------------------------------------------------------------------------
// mean over heads commutes with einsum+mean -> pre-average weights (4x FLOPs cut)
// ---------------------------------------------------------------------------
__global__ void avg_weights_kernel(const float* __restrict__ Ws,
                                   const float* __restrict__ Wn,
                                   const float* __restrict__ b,
                                   float* __restrict__ wavg) {
    int i = blockIdx.x * 256 + threadIdx.x;
    if (i < DIM * DIM) {
        float s = 0.f, n = 0.f;
#pragma unroll
        for (int hh = 0; hh < NH; ++hh) {
            s += Ws[hh * DIM * DIM + i];
            n += Wn[hh * DIM * DIM + i];
        }
        wavg[i] = 0.25f * s;
        wavg[DIM * DIM + i] = 0.25f * n;
    }
    if (i < DIM) {
        float bb = 0.f;
#pragma unroll
        for (int hh = 0; hh < NH; ++hh) bb += b[hh * DIM + i];
        wavg[2 * DIM * DIM + i] = 0.25f * bb;
    }
}

// ---------------------------------------------------------------------------
// 1) degree histogram (int atomics into L2-resident 400KB array)
// ---------------------------------------------------------------------------
__global__ __launch_bounds__(256) void deg_hist_kernel(const int* __restrict__ dst,
                                                       int* __restrict__ cnt) {
    int e = blockIdx.x * 256 + threadIdx.x;
    atomicAdd(&cnt[dst[e]], 1);
}

// ---------------------------------------------------------------------------
// 2a) per-block exclusive scan (1 elem/thread, LDS Hillis-Steele), block sums
//     out; zeroes cnt so it becomes the fill cursor.
// ---------------------------------------------------------------------------
__global__ __launch_bounds__(SCAN_BLK) void scan1_kernel(int* __restrict__ cnt,
                                                         int* __restrict__ rowoff,
                                                         int* __restrict__ blksum) {
    __shared__ int sums[SCAN_BLK];
    int t = threadIdx.x;
    int i = blockIdx.x * SCAN_BLK + t;
    int v = (i < N_NODES) ? cnt[i] : 0;
    if (i < N_NODES) cnt[i] = 0;
    sums[t] = v;
    __syncthreads();
    for (int off = 1; off < SCAN_BLK; off <<= 1) {
        int add = (t >= off) ? sums[t - off] : 0;
        __syncthreads();
        sums[t] += add;
        __syncthreads();
    }
    if (i < N_NODES) rowoff[i] = sums[t] - v;  // block-local exclusive
    if (t == SCAN_BLK - 1) blksum[blockIdx.x] = sums[t];
}

// ---------------------------------------------------------------------------
// 2b) scan the 98 block sums (one tiny block)
// ---------------------------------------------------------------------------
__global__ __launch_bounds__(128) void scan2_kernel(int* __restrict__ blksum) {
    __shared__ int s[128];
    int t = threadIdx.x;
    int v = (t < SCAN_NB) ? blksum[t] : 0;
    s[t] = v;
    __syncthreads();
    for (int off = 1; off < 128; off <<= 1) {
        int add = (t >= off) ? s[t - off] : 0;
        __syncthreads();
        s[t] += add;
        __syncthreads();
    }
    if (t < SCAN_NB) blksum[t] = s[t] - v;  // exclusive
}

// ---------------------------------------------------------------------------
// 2c) add block offsets; total slot is the compile-time edge count
// ---------------------------------------------------------------------------
__global__ __launch_bounds__(SCAN_BLK) void scan3_kernel(int* __restrict__ rowoff,
                                                         const int* __restrict__ blksum) {
    int i = blockIdx.x * SCAN_BLK + threadIdx.x;
    if (i < N_NODES) rowoff[i] += blksum[blockIdx.x];
    if (i == 0) rowoff[N_NODES] = N_EDGES;
}

// ---------------------------------------------------------------------------
// 3) bucket edges by dst: csr[rowoff[d] + cursor[d]++] = src
// ---------------------------------------------------------------------------
__global__ __launch_bounds__(256) void fill_csr_kernel(const int* __restrict__ src,
                                                       const int* __restrict__ dst,
                                                       const int* __restrict__ rowoff,
                                                       int* __restrict__ cursor,
                                                       int* __restrict__ csr) {
    int e = blockIdx.x * 256 + threadIdx.x;
    int d = dst[e];
    int pos = rowoff[d] + atomicAdd(&cursor[d], 1);
    csr[pos] = src[e];
}

// ---------------------------------------------------------------------------
// 4) gather-mean: one 64-lane wave per node, float2 per lane (512B/row/wave).
//    csr index is wave-uniform -> scalar loads. out = sum(h[src]) / max(deg,1).
// ---------------------------------------------------------------------------
__global__ __launch_bounds__(256) void gather_mean_kernel(const float* __restrict__ h,
                                                          const int* __restrict__ rowoff,
                                                          const int* __restrict__ csr,
                                                          float* __restrict__ out) {
    int node = blockIdx.x * 4 + (threadIdx.x >> 6);
    int lane = threadIdx.x & 63;
    int lo = rowoff[node];
    int hi = rowoff[node + 1];
    const float2* h2 = reinterpret_cast<const float2*>(h);
    float ax = 0.f, ay = 0.f;
    int k = lo;
    for (; k + 3 < hi; k += 4) {  // unroll-4: 4 independent loads in flight
        int s0 = csr[k], s1 = csr[k + 1], s2 = csr[k + 2], s3 = csr[k + 3];
        float2 v0 = h2[(size_t)s0 * 64 + lane];
        float2 v1 = h2[(size_t)s1 * 64 + lane];
        float2 v2 = h2[(size_t)s2 * 64 + lane];
        float2 v3 = h2[(size_t)s3 * 64 + lane];
        ax += v0.x + v1.x + v2.x + v3.x;
        ay += v0.y + v1.y + v2.y + v3.y;
    }
    for (; k < hi; ++k) {
        int s0 = csr[k];
        float2 v0 = h2[(size_t)s0 * 64 + lane];
        ax += v0.x;
        ay += v0.y;
    }
    float inv = 1.0f / (float)max(hi - lo, 1);
    reinterpret_cast<float2*>(out)[(size_t)node * 64 + lane] = make_float2(ax * inv, ay * inv);
}

// ---------------------------------------------------------------------------
// 5) fused GEMM: out[n] = h[n]@Ws + hn[n]@Wn + bavg   (hn lives in `out`,
//    overwritten in place; row-local dependency).
// ---------------------------------------------------------------------------
__global__ __launch_bounds__(256) void fused_gemm_kernel(const float* __restrict__ h,
                                                         float* __restrict__ out,
                                                         const float* __restrict__ wavg) {
    __shared__ float hsT[DIM][LDST];
    __shared__ float nsT[DIM][LDST];
    const float* Ws = wavg;
    const float* Wn = wavg + DIM * DIM;
    const float* bavg = wavg + 2 * DIM * DIM;
    const int tile = blockIdx.x * TILE_N;
    const int tid = threadIdx.x;

    for (int i = tid; i < TILE_N * (DIM / 4); i += 256) {
        int n = i & 31;
        int c = i >> 5;
        size_t row = (size_t)(tile + n) * DIM;
        float4 hv = reinterpret_cast<const float4*>(h + row)[c];
        float4 nv = reinterpret_cast<const float4*>(out + row)[c];
        int d0 = c * 4;
        hsT[d0 + 0][n] = hv.x; hsT[d0 + 1][n] = hv.y;
        hsT[d0 + 2][n] = hv.z; hsT[d0 + 3][n] = hv.w;
        nsT[d0 + 0][n] = nv.x; nsT[d0 + 1][n] = nv.y;
        nsT[d0 + 2][n] = nv.z; nsT[d0 + 3][n] = nv.w;
    }
    __syncthreads();

    const int og = tid & 31;
    const int ng = tid >> 5;
    const int n0 = ng * 4;

    float accS[4][4] = {{0.f}};
    float accN[4][4] = {{0.f}};

    for (int d = 0; d < DIM; ++d) {
        float4 a  = *reinterpret_cast<const float4*>(&hsT[d][n0]);
        float4 an = *reinterpret_cast<const float4*>(&nsT[d][n0]);
        float4 ws = reinterpret_cast<const float4*>(Ws + d * DIM)[og];
        float4 wn = reinterpret_cast<const float4*>(Wn + d * DIM)[og];
        float av[4]  = {a.x, a.y, a.z, a.w};
        float nv[4]  = {an.x, an.y, an.z, an.w};
        float wsv[4] = {ws.x, ws.y, ws.z, ws.w};
        float wnv[4] = {wn.x, wn.y, wn.z, wn.w};
#pragma unroll
        for (int i = 0; i < 4; ++i)
#pragma unroll
            for (int j = 0; j < 4; ++j) {
                accS[i][j] = fmaf(av[i], wsv[j], accS[i][j]);
                accN[i][j] = fmaf(nv[i], wnv[j], accN[i][j]);
            }
    }

    float4 bb = reinterpret_cast<const float4*>(bavg)[og];
    float bv[4] = {bb.x, bb.y, bb.z, bb.w};
#pragma unroll
    for (int i = 0; i < 4; ++i) {
        int node = tile + n0 + i;
        float4 r;
        r.x = accS[i][0] + accN[i][0] + bv[0];
        r.y = accS[i][1] + accN[i][1] + bv[1];
        r.z = accS[i][2] + accN[i][2] + bv[2];
        r.w = accS[i][3] + accN[i][3] + bv[3];
        reinterpret_cast<float4*>(out + (size_t)node * DIM)[og] = r;
    }
}

extern "C" void kernel_launch(void* const* d_in, const int* in_sizes, int n_in,
                              void* d_out, int out_size, void* d_ws, size_t ws_size,
                              hipStream_t stream) {
    const float* h  = (const float*)d_in[0];
    const int* src  = (const int*)d_in[1];
    const int* dst  = (const int*)d_in[2];
    const float* Ws = (const float*)d_in[3];
    const float* Wn = (const float*)d_in[4];
    const float* b  = (const float*)d_in[5];
    float* out = (float*)d_out;

    int* wsi    = (int*)d_ws;
    int* rowoff = wsi + OFF_ROWOFF;
    int* cursor = wsi + OFF_CURSOR;
    int* blksum = wsi + OFF_BLKSUM;
    int* csr    = wsi + OFF_CSR;
    float* wavg = (float*)d_ws + OFF_WAVG;

    hipMemsetAsync(cursor, 0, N_NODES * sizeof(int), stream);

    avg_weights_kernel<<<(DIM * DIM + 255) / 256, 256, 0, stream>>>(Ws, Wn, b, wavg);
    deg_hist_kernel<<<N_EDGES / 256, 256, 0, stream>>>(dst, cursor);
    scan1_kernel<<<SCAN_NB, SCAN_BLK, 0, stream>>>(cursor, rowoff, blksum);
    scan2_kernel<<<1, 128, 0, stream>>>(blksum);
    scan3_kernel<<<SCAN_NB, SCAN_BLK, 0, stream>>>(rowoff, blksum);
    fill_csr_kernel<<<N_EDGES / 256, 256, 0, stream>>>(src, dst, rowoff, cursor, csr);
    gather_mean_kernel<<<N_NODES / 4, 256, 0, stream>>>(h, rowoff, csr, out);
    fused_gemm_kernel<<<N_NODES / TILE_N, 256, 0, stream>>>(h, out, wavg);
}

// Round 4
// 285.754 us; speedup vs baseline: 10.1550x; 1.4582x over previous
//
#include <hip/hip_runtime.h>

#define N_NODES 100000
#define N_EDGES 1600000
#define DIM 128
#define NH 4

#define SCAN_BLK 1024
#define SCAN_NB ((N_NODES + SCAN_BLK - 1) / SCAN_BLK)  // 98

typedef __attribute__((ext_vector_type(8))) short bf16x8;
typedef __attribute__((ext_vector_type(4))) float f32x4;
typedef __attribute__((ext_vector_type(8))) unsigned short u16x8;

// ws layout, BYTE offsets (all 16B-aligned):
//   rowoff : [0, 401408)            int, deg exclusive scan (+1 total slot)
//   cursor : [401408, 802816)       int, histogram then fill cursor
//   blksum : [802816, 803328)       int, per-block scan totals
//   csr    : [803328, 7203328)      int, src ids bucketed by dst
//   wpack  : [7203328, 7268864)     bf16, MFMA-fragment-packed Ws|Wn (32KB each)
//   bavg   : [7268864, 7269376)     f32, averaged bias
//   hb     : [7269376, 32869376)    bf16 copy of h (only if ws allows)
#define B_ROWOFF 0u
#define B_CURSOR 401408u
#define B_BLKSUM 802816u
#define B_CSR    803328u
#define B_WPACK  7203328u
#define B_BAVG   7268864u
#define B_HB     7269376u
#define NEED_BF16 32869376ull

// branchless RTNE f32->bf16 (inputs are finite random normals; no NaN path)
__device__ inline unsigned short f2bf(float x) {
    union { float f; unsigned u; } v; v.f = x;
    unsigned r = v.u + 0x7fffu + ((v.u >> 16) & 1u);
    return (unsigned short)(r >> 16);
}

// ---------------------------------------------------------------------------
// Head-average weights (mean over heads commutes with einsum+mean), then pack
// into MFMA B-fragment order: frag(nt,ks), lane l holds col=nt*16+(l&15),
// k = ks*32 + (l>>4)*8 + e, e=0..7 contiguous -> one 16B load per frag.
// ---------------------------------------------------------------------------
__global__ __launch_bounds__(256) void prep_weights_kernel(
    const float* __restrict__ Ws, const float* __restrict__ Wn,
    const float* __restrict__ b, unsigned short* __restrict__ wpack,
    float* __restrict__ bavg) {
    int i = blockIdx.x * 256 + threadIdx.x;  // i = k*128 + o
    if (i < DIM * DIM) {
        float s = 0.f, n = 0.f;
#pragma unroll
        for (int hh = 0; hh < NH; ++hh) {
            s += Ws[hh * DIM * DIM + i];
            n += Wn[hh * DIM * DIM + i];
        }
        s *= 0.25f; n *= 0.25f;
        int k = i >> 7, o = i & 127;
        int nt = o >> 4, lanelo = o & 15;
        int ks = k >> 5, lanehi = (k & 31) >> 3, e = k & 7;
        int pos = (((nt * 4 + ks) * 64) + lanehi * 16 + lanelo) * 8 + e;
        wpack[pos] = f2bf(s);
        wpack[16384 + pos] = f2bf(n);
    }
    if (i < DIM) {
        float bb = 0.f;
#pragma unroll
        for (int hh = 0; hh < NH; ++hh) bb += b[hh * DIM + i];
        bavg[i] = 0.25f * bb;
    }
}

// ---------------------------------------------------------------------------
// h -> bf16 copy (halves gather read traffic; direct MFMA A-frags)
// ---------------------------------------------------------------------------
__global__ __launch_bounds__(256) void h2bf16_kernel(const float* __restrict__ h,
                                                     unsigned short* __restrict__ hb) {
    int i = blockIdx.x * 256 + threadIdx.x;  // 8 elems per thread
    const float4* p = reinterpret_cast<const float4*>(h) + (size_t)i * 2;
    float4 a = p[0], c = p[1];
    u16x8 r;
    r[0] = f2bf(a.x); r[1] = f2bf(a.y); r[2] = f2bf(a.z); r[3] = f2bf(a.w);
    r[4] = f2bf(c.x); r[5] = f2bf(c.y); r[6] = f2bf(c.z); r[7] = f2bf(c.w);
    reinterpret_cast<u16x8*>(hb)[i] = r;
}

// ---------------------------------------------------------------------------
// degree histogram (int atomics, L2-resident 400KB)
// ---------------------------------------------------------------------------
__global__ __launch_bounds__(256) void deg_hist_kernel(const int* __restrict__ dst,
                                                       int* __restrict__ cnt) {
    int e = blockIdx.x * 256 + threadIdx.x;
    atomicAdd(&cnt[dst[e]], 1);
}

// ---------------------------------------------------------------------------
// device-wide exclusive scan, 3 dispatches
// ---------------------------------------------------------------------------
__global__ __launch_bounds__(SCAN_BLK) void scan1_kernel(int* __restrict__ cnt,
                                                         int* __restrict__ rowoff,
                                                         int* __restrict__ blksum) {
    __shared__ int sums[SCAN_BLK];
    int t = threadIdx.x;
    int i = blockIdx.x * SCAN_BLK + t;
    int v = (i < N_NODES) ? cnt[i] : 0;
    if (i < N_NODES) cnt[i] = 0;
    sums[t] = v;
    __syncthreads();
    for (int off = 1; off < SCAN_BLK; off <<= 1) {
        int add = (t >= off) ? sums[t - off] : 0;
        __syncthreads();
        sums[t] += add;
        __syncthreads();
    }
    if (i < N_NODES) rowoff[i] = sums[t] - v;
    if (t == SCAN_BLK - 1) blksum[blockIdx.x] = sums[t];
}

__global__ __launch_bounds__(128) void scan2_kernel(int* __restrict__ blksum) {
    __shared__ int s[128];
    int t = threadIdx.x;
    int v = (t < SCAN_NB) ? blksum[t] : 0;
    s[t] = v;
    __syncthreads();
    for (int off = 1; off < 128; off <<= 1) {
        int add = (t >= off) ? s[t - off] : 0;
        __syncthreads();
        s[t] += add;
        __syncthreads();
    }
    if (t < SCAN_NB) blksum[t] = s[t] - v;
}

__global__ __launch_bounds__(SCAN_BLK) void scan3_kernel(int* __restrict__ rowoff,
                                                         const int* __restrict__ blksum) {
    int i = blockIdx.x * SCAN_BLK + threadIdx.x;
    if (i < N_NODES) rowoff[i] += blksum[blockIdx.x];
    if (i == 0) rowoff[N_NODES] = N_EDGES;
}

// ---------------------------------------------------------------------------
// bucket edges by dst
// ---------------------------------------------------------------------------
__global__ __launch_bounds__(256) void fill_csr_kernel(const int* __restrict__ src,
                                                       const int* __restrict__ dst,
                                                       const int* __restrict__ rowoff,
                                                       int* __restrict__ cursor,
                                                       int* __restrict__ csr) {
    int e = blockIdx.x * 256 + threadIdx.x;
    int d = dst[e];
    int pos = rowoff[d] + atomicAdd(&cursor[d], 1);
    csr[pos] = src[e];
}

// ---------------------------------------------------------------------------
// gather-mean: one wave per node; BF path reads bf16 rows (256B/row).
// Writes fp32 h_neigh into `out` (consumed in place by the GEMM).
// ---------------------------------------------------------------------------
template <bool BF>
__global__ __launch_bounds__(256) void gather_mean_kernel(
    const float* __restrict__ h, const unsigned short* __restrict__ hb,
    const int* __restrict__ rowoff, const int* __restrict__ csr,
    float* __restrict__ out) {
    int node = blockIdx.x * 4 + (threadIdx.x >> 6);
    int lane = threadIdx.x & 63;
    int lo = rowoff[node];
    int hi = rowoff[node + 1];
    float ax = 0.f, ay = 0.f;
    int k = lo;
    if (BF) {
        const unsigned* h1 = reinterpret_cast<const unsigned*>(hb);
        for (; k + 3 < hi; k += 4) {
            int s0 = csr[k], s1 = csr[k + 1], s2 = csr[k + 2], s3 = csr[k + 3];
            unsigned v0 = h1[(size_t)s0 * 64 + lane];
            unsigned v1 = h1[(size_t)s1 * 64 + lane];
            unsigned v2 = h1[(size_t)s2 * 64 + lane];
            unsigned v3 = h1[(size_t)s3 * 64 + lane];
            ax += __uint_as_float(v0 << 16) + __uint_as_float(v1 << 16) +
                  __uint_as_float(v2 << 16) + __uint_as_float(v3 << 16);
            ay += __uint_as_float(v0 & 0xffff0000u) + __uint_as_float(v1 & 0xffff0000u) +
                  __uint_as_float(v2 & 0xffff0000u) + __uint_as_float(v3 & 0xffff0000u);
        }
        for (; k < hi; ++k) {
            unsigned v0 = h1[(size_t)csr[k] * 64 + lane];
            ax += __uint_as_float(v0 << 16);
            ay += __uint_as_float(v0 & 0xffff0000u);
        }
    } else {
        const float2* h2 = reinterpret_cast<const float2*>(h);
        for (; k + 3 < hi; k += 4) {
            int s0 = csr[k], s1 = csr[k + 1], s2 = csr[k + 2], s3 = csr[k + 3];
            float2 v0 = h2[(size_t)s0 * 64 + lane];
            float2 v1 = h2[(size_t)s1 * 64 + lane];
            float2 v2 = h2[(size_t)s2 * 64 + lane];
            float2 v3 = h2[(size_t)s3 * 64 + lane];
            ax += v0.x + v1.x + v2.x + v3.x;
            ay += v0.y + v1.y + v2.y + v3.y;
        }
        for (; k < hi; ++k) {
            float2 v0 = h2[(size_t)csr[k] * 64 + lane];
            ax += v0.x;
            ay += v0.y;
        }
    }
    float inv = 1.0f / (float)max(hi - lo, 1);
    reinterpret_cast<float2*>(out)[(size_t)node * 64 + lane] = make_float2(ax * inv, ay * inv);
}

// ---------------------------------------------------------------------------
// MFMA GEMM: out[n] = h[n]@Ws + hn[n]@Wn + bavg. hn is read from `out` and
// overwritten in place — wave-local (each wave reads/writes only its 16 rows).
// Wave = 16 nodes x 128 outs; 4 k-steps x 16 mfma_f32_16x16x32_bf16.
// No LDS, no barriers; B-frags are 16B loads from the packed weights (L1/L2).
// ---------------------------------------------------------------------------
template <bool BF>
__global__ __launch_bounds__(256) void mfma_gemm_kernel(
    const float* __restrict__ h, const unsigned short* __restrict__ hb,
    float* __restrict__ out, const unsigned short* __restrict__ wpack,
    const float* __restrict__ bavg) {
    const int lane = threadIdx.x & 63;
    const int wid = threadIdx.x >> 6;
    const int node_base = blockIdx.x * 64 + wid * 16;
    const int row = node_base + (lane & 15);
    const int rowc = min(row, N_NODES - 1);  // tail clamp: reads valid, stores guarded
    const int khi = lane >> 4;

    f32x4 acc[8] = {};
    const unsigned short* wn_p = wpack + 16384;

#pragma unroll
    for (int ks = 0; ks < 4; ++ks) {
        const int k0 = ks * 32 + khi * 8;
        bf16x8 ha, na;
        if (BF) {
            ha = *reinterpret_cast<const bf16x8*>(hb + (size_t)rowc * DIM + k0);
        } else {
            const float4* hp = reinterpret_cast<const float4*>(h + (size_t)rowc * DIM + k0);
            float4 x = hp[0], y = hp[1];
            ha[0] = (short)f2bf(x.x); ha[1] = (short)f2bf(x.y);
            ha[2] = (short)f2bf(x.z); ha[3] = (short)f2bf(x.w);
            ha[4] = (short)f2bf(y.x); ha[5] = (short)f2bf(y.y);
            ha[6] = (short)f2bf(y.z); ha[7] = (short)f2bf(y.w);
        }
        const float4* np0 = reinterpret_cast<const float4*>(out + (size_t)rowc * DIM + k0);
        float4 u = np0[0], v = np0[1];
        na[0] = (short)f2bf(u.x); na[1] = (short)f2bf(u.y);
        na[2] = (short)f2bf(u.z); na[3] = (short)f2bf(u.w);
        na[4] = (short)f2bf(v.x); na[5] = (short)f2bf(v.y);
        na[6] = (short)f2bf(v.z); na[7] = (short)f2bf(v.w);

#pragma unroll
        for (int nt = 0; nt < 8; ++nt) {
            bf16x8 bs = *reinterpret_cast<const bf16x8*>(wpack + (size_t)(((nt * 4 + ks) * 64 + lane) * 8));
            acc[nt] = __builtin_amdgcn_mfma_f32_16x16x32_bf16(ha, bs, acc[nt], 0, 0, 0);
            bf16x8 bn = *reinterpret_cast<const bf16x8*>(wn_p + (size_t)(((nt * 4 + ks) * 64 + lane) * 8));
            acc[nt] = __builtin_amdgcn_mfma_f32_16x16x32_bf16(na, bn, acc[nt], 0, 0, 0);
        }
    }

    // C/D layout (verified m89): col = lane&15, row = (lane>>4)*4 + reg
    const int r0 = node_base + khi * 4;
#pragma unroll
    for (int nt = 0; nt < 8; ++nt) {
        int o = nt * 16 + (lane & 15);
        float bb = bavg[o];
#pragma unroll
        for (int r = 0; r < 4; ++r) {
            int nr = r0 + r;
            if (nr < N_NODES) out[(size_t)nr * DIM + o] = acc[nt][r] + bb;
        }
    }
}

extern "C" void kernel_launch(void* const* d_in, const int* in_sizes, int n_in,
                              void* d_out, int out_size, void* d_ws, size_t ws_size,
                              hipStream_t stream) {
    const float* h  = (const float*)d_in[0];
    const int* src  = (const int*)d_in[1];
    const int* dst  = (const int*)d_in[2];
    const float* Ws = (const float*)d_in[3];
    const float* Wn = (const float*)d_in[4];
    const float* b  = (const float*)d_in[5];
    float* out = (float*)d_out;

    char* ws = (char*)d_ws;
    int* rowoff = (int*)(ws + B_ROWOFF);
    int* cursor = (int*)(ws + B_CURSOR);
    int* blksum = (int*)(ws + B_BLKSUM);
    int* csr    = (int*)(ws + B_CSR);
    unsigned short* wpack = (unsigned short*)(ws + B_WPACK);
    float* bavg = (float*)(ws + B_BAVG);
    unsigned short* hb = (unsigned short*)(ws + B_HB);

    const bool bf = (ws_size >= NEED_BF16);  // fixed per session -> deterministic

    hipMemsetAsync(cursor, 0, N_NODES * sizeof(int), stream);

    prep_weights_kernel<<<64, 256, 0, stream>>>(Ws, Wn, b, wpack, bavg);
    if (bf) h2bf16_kernel<<<(N_NODES * DIM / 8) / 256, 256, 0, stream>>>(h, hb);
    deg_hist_kernel<<<N_EDGES / 256, 256, 0, stream>>>(dst, cursor);
    scan1_kernel<<<SCAN_NB, SCAN_BLK, 0, stream>>>(cursor, rowoff, blksum);
    scan2_kernel<<<1, 128, 0, stream>>>(blksum);
    scan3_kernel<<<SCAN_NB, SCAN_BLK, 0, stream>>>(rowoff, blksum);
    fill_csr_kernel<<<N_EDGES / 256, 256, 0, stream>>>(src, dst, rowoff, cursor, csr);
    if (bf)
        gather_mean_kernel<true><<<N_NODES / 4, 256, 0, stream>>>(h, hb, rowoff, csr, out);
    else
        gather_mean_kernel<false><<<N_NODES / 4, 256, 0, stream>>>(h, hb, rowoff, csr, out);
    const int gemm_blocks = (N_NODES + 63) / 64;
    if (bf)
        mfma_gemm_kernel<true><<<gemm_blocks, 256, 0, stream>>>(h, hb, out, wpack, bavg);
    else
        mfma_gemm_kernel<false><<<gemm_blocks, 256, 0, stream>>>(h, hb, out, wpack, bavg);
}

// Round 5
// 202.585 us; speedup vs baseline: 14.3240x; 1.4105x over previous
//
#include <hip/hip_runtime.h>

#define N_NODES 100000
#define N_EDGES 1600000
#define DIM 128
#define NH 4

#define NPB 512                                   // nodes per coarse bucket
#define NB 196                                    // ceil(N_NODES / NPB)
#define BCHUNK 2048                               // edges per block (bucket passes)
#define BEPT 8                                    // BCHUNK / 256
#define NBLK ((N_EDGES + BCHUNK - 1) / BCHUNK)    // 782

typedef __attribute__((ext_vector_type(8))) short bf16x8;
typedef __attribute__((ext_vector_type(4))) float f32x4;
typedef __attribute__((ext_vector_type(8))) unsigned short u16x8;

// ws layout, BYTE offsets (16B-aligned where it matters):
//   bcnt   : [0, 1024)           int[256] coarse bucket counts
//   bbase  : [1024, 2048)        int[256] bucket bases (excl scan)
//   bcur   : [2048, 3072)        int[256] bucket fill cursors
//   rowoff : [4096, 405504)      int[100001] node-level CSR offsets
//   csr    : [405504, 6805504)   int[1.6M] src ids bucketed+sorted by dst
//   wpack  : [6805504, 6871040)  bf16 MFMA-packed Ws|Wn
//   bavg   : [6871040, 6871552)  f32[128]
//   hb     : [6871552, 32471552) bf16 copy of h (25.6MB)
//   ebuf   : aliases hb region   int[1.6M] packed (src<<9|dstlo); dead before h2bf16
#define B_BCNT   0u
#define B_BBASE  1024u
#define B_BCUR   2048u
#define B_ROWOFF 4096u
#define B_CSR    405504u
#define B_WPACK  6805504u
#define B_BAVG   6871040u
#define B_HB     6871552u
#define B_EBUF   6871552u
#define NEED_BF16 32869376ull

// branchless RTNE f32->bf16 (finite inputs; no NaN path)
__device__ inline unsigned short f2bf(float x) {
    union { float f; unsigned u; } v; v.f = x;
    unsigned r = v.u + 0x7fffu + ((v.u >> 16) & 1u);
    return (unsigned short)(r >> 16);
}

// ---------------------------------------------------------------------------
// Head-average weights (mean over heads commutes with einsum+mean), pack into
// MFMA B-frag order: frag(nt,ks), lane l: col=nt*16+(l&15), k=ks*32+(l>>4)*8+e.
// ---------------------------------------------------------------------------
__global__ __launch_bounds__(256) void prep_weights_kernel(
    const float* __restrict__ Ws, const float* __restrict__ Wn,
    const float* __restrict__ b, unsigned short* __restrict__ wpack,
    float* __restrict__ bavg) {
    int i = blockIdx.x * 256 + threadIdx.x;  // i = k*128 + o
    if (i < DIM * DIM) {
        float s = 0.f, n = 0.f;
#pragma unroll
        for (int hh = 0; hh < NH; ++hh) {
            s += Ws[hh * DIM * DIM + i];
            n += Wn[hh * DIM * DIM + i];
        }
        s *= 0.25f; n *= 0.25f;
        int k = i >> 7, o = i & 127;
        int nt = o >> 4, lanelo = o & 15;
        int ks = k >> 5, lanehi = (k & 31) >> 3, e = k & 7;
        int pos = (((nt * 4 + ks) * 64) + lanehi * 16 + lanelo) * 8 + e;
        wpack[pos] = f2bf(s);
        wpack[16384 + pos] = f2bf(n);
    }
    if (i < DIM) {
        float bb = 0.f;
#pragma unroll
        for (int hh = 0; hh < NH; ++hh) bb += b[hh * DIM + i];
        bavg[i] = 0.25f * bb;
    }
}

// ---------------------------------------------------------------------------
// h -> bf16 copy (halves gather read stream; direct MFMA A-frags)
// ---------------------------------------------------------------------------
__global__ __launch_bounds__(256) void h2bf16_kernel(const float* __restrict__ h,
                                                     unsigned short* __restrict__ hb) {
    int i = blockIdx.x * 256 + threadIdx.x;  // 8 elems/thread
    const float4* p = reinterpret_cast<const float4*>(h) + (size_t)i * 2;
    float4 a = p[0], c = p[1];
    u16x8 r;
    r[0] = f2bf(a.x); r[1] = f2bf(a.y); r[2] = f2bf(a.z); r[3] = f2bf(a.w);
    r[4] = f2bf(c.x); r[5] = f2bf(c.y); r[6] = f2bf(c.z); r[7] = f2bf(c.w);
    reinterpret_cast<u16x8*>(hb)[i] = r;
}

// ---------------------------------------------------------------------------
// P1a: coarse histogram (bucket = dst>>9) via LDS counters
// ---------------------------------------------------------------------------
__global__ __launch_bounds__(256) void bucket_hist_kernel(const int* __restrict__ dst,
                                                          int* __restrict__ bcnt) {
    __shared__ int lc[256];
    int t = threadIdx.x;
    lc[t] = 0;
    __syncthreads();
    int e0 = blockIdx.x * BCHUNK;
#pragma unroll
    for (int j = 0; j < BEPT; ++j) {
        int e = e0 + j * 256 + t;
        if (e < N_EDGES) atomicAdd(&lc[dst[e] >> 9], 1);
    }
    __syncthreads();
    if (lc[t]) atomicAdd(&bcnt[t], lc[t]);
}

// ---------------------------------------------------------------------------
// P1b: scan 256 bucket counts -> bases; init cursors
// ---------------------------------------------------------------------------
__global__ __launch_bounds__(256) void bucket_scan_kernel(const int* __restrict__ bcnt,
                                                          int* __restrict__ bbase,
                                                          int* __restrict__ bcur) {
    __shared__ int s[256];
    int t = threadIdx.x;
    int v = bcnt[t];
    s[t] = v;
    __syncthreads();
    for (int off = 1; off < 256; off <<= 1) {
        int add = (t >= off) ? s[t - off] : 0;
        __syncthreads();
        s[t] += add;
        __syncthreads();
    }
    int ex = s[t] - v;
    bbase[t] = ex;
    bcur[t] = ex;
}

// ---------------------------------------------------------------------------
// P1c: bucket the edges. Block stages 2048 packed edges in LDS, reserves one
// contiguous chunk per bucket (1 global atomic/bucket/block), appends runs.
// Packed word: (src<<9) | (dst & 511)  -- 17+9 = 26 bits.
// ---------------------------------------------------------------------------
__global__ __launch_bounds__(256) void bucket_scatter_kernel(const int* __restrict__ src,
                                                             const int* __restrict__ dst,
                                                             int* __restrict__ bcur,
                                                             int* __restrict__ ebuf) {
    __shared__ int stage[BCHUNK];
    __shared__ int lc[256], lbase[256], lpos[256];
    int t = threadIdx.x;
    lc[t] = 0;
    lpos[t] = 0;
    __syncthreads();
    int e0 = blockIdx.x * BCHUNK;
#pragma unroll
    for (int j = 0; j < BEPT; ++j) {
        int e = e0 + j * 256 + t;
        if (e < N_EDGES) {
            int d = dst[e];
            stage[j * 256 + t] = (src[e] << 9) | (d & (NPB - 1));
            atomicAdd(&lc[d >> 9], 1);
        }
    }
    __syncthreads();
    if (lc[t]) lbase[t] = atomicAdd(&bcur[t], lc[t]);
    __syncthreads();
#pragma unroll
    for (int j = 0; j < BEPT; ++j) {
        int e = e0 + j * 256 + t;
        if (e < N_EDGES) {
            int b = dst[e] >> 9;
            int o = atomicAdd(&lpos[b], 1);
            ebuf[lbase[b] + o] = stage[j * 256 + t];
        }
    }
}

// ---------------------------------------------------------------------------
// P2: one block per bucket. Local 512-slot hist + scan -> rowoff (node-level
// CSR offsets, replaces old global hist+scan), then scatter src into csr
// within the bucket's contiguous (L2-resident) window.
// ---------------------------------------------------------------------------
__global__ __launch_bounds__(256) void csr_build_kernel(const int* __restrict__ bcnt,
                                                        const int* __restrict__ bbase,
                                                        const int* __restrict__ ebuf,
                                                        int* __restrict__ rowoff,
                                                        int* __restrict__ csr) {
    __shared__ int h[NPB], off[NPB], cur[NPB], ss[256];
    int b = blockIdx.x, t = threadIdx.x;
    int cnt = bcnt[b], base = bbase[b];
    h[t] = 0; h[t + 256] = 0;
    cur[t] = 0; cur[t + 256] = 0;
    __syncthreads();
    for (int i = t; i < cnt; i += 256) atomicAdd(&h[ebuf[base + i] & (NPB - 1)], 1);
    __syncthreads();
    int e0 = h[2 * t], e1 = h[2 * t + 1];
    ss[t] = e0 + e1;
    __syncthreads();
    for (int o = 1; o < 256; o <<= 1) {
        int add = (t >= o) ? ss[t - o] : 0;
        __syncthreads();
        ss[t] += add;
        __syncthreads();
    }
    int ex = ss[t] - (e0 + e1);
    off[2 * t] = ex;
    off[2 * t + 1] = ex + e0;
    __syncthreads();
    int n0 = b * NPB;
#pragma unroll
    for (int k = 0; k < 2; ++k) {
        int s2 = t + k * 256;
        int n = n0 + s2;
        if (n <= N_NODES) rowoff[n] = base + off[s2];
    }
    for (int i = t; i < cnt; i += 256) {
        int p = ebuf[base + i];
        int nl = p & (NPB - 1);
        int o = atomicAdd(&cur[nl], 1);
        csr[base + off[nl] + o] = p >> 9;
    }
}

// ---------------------------------------------------------------------------
// gather-mean: one wave per node; bf path reads 256B/row.
// Writes fp32 h_neigh into `out` (consumed in place by the GEMM).
// ---------------------------------------------------------------------------
template <bool BF>
__global__ __launch_bounds__(256) void gather_mean_kernel(
    const float* __restrict__ h, const unsigned short* __restrict__ hb,
    const int* __restrict__ rowoff, const int* __restrict__ csr,
    float* __restrict__ out) {
    int node = blockIdx.x * 4 + (threadIdx.x >> 6);
    int lane = threadIdx.x & 63;
    int lo = rowoff[node];
    int hi = rowoff[node + 1];
    float ax = 0.f, ay = 0.f;
    int k = lo;
    if (BF) {
        const unsigned* h1 = reinterpret_cast<const unsigned*>(hb);
        for (; k + 3 < hi; k += 4) {
            int s0 = csr[k], s1 = csr[k + 1], s2 = csr[k + 2], s3 = csr[k + 3];
            unsigned v0 = h1[(size_t)s0 * 64 + lane];
            unsigned v1 = h1[(size_t)s1 * 64 + lane];
            unsigned v2 = h1[(size_t)s2 * 64 + lane];
            unsigned v3 = h1[(size_t)s3 * 64 + lane];
            ax += __uint_as_float(v0 << 16) + __uint_as_float(v1 << 16) +
                  __uint_as_float(v2 << 16) + __uint_as_float(v3 << 16);
            ay += __uint_as_float(v0 & 0xffff0000u) + __uint_as_float(v1 & 0xffff0000u) +
                  __uint_as_float(v2 & 0xffff0000u) + __uint_as_float(v3 & 0xffff0000u);
        }
        for (; k < hi; ++k) {
            unsigned v0 = h1[(size_t)csr[k] * 64 + lane];
            ax += __uint_as_float(v0 << 16);
            ay += __uint_as_float(v0 & 0xffff0000u);
        }
    } else {
        const float2* h2 = reinterpret_cast<const float2*>(h);
        for (; k + 3 < hi; k += 4) {
            int s0 = csr[k], s1 = csr[k + 1], s2 = csr[k + 2], s3 = csr[k + 3];
            float2 v0 = h2[(size_t)s0 * 64 + lane];
            float2 v1 = h2[(size_t)s1 * 64 + lane];
            float2 v2 = h2[(size_t)s2 * 64 + lane];
            float2 v3 = h2[(size_t)s3 * 64 + lane];
            ax += v0.x + v1.x + v2.x + v3.x;
            ay += v0.y + v1.y + v2.y + v3.y;
        }
        for (; k < hi; ++k) {
            float2 v0 = h2[(size_t)csr[k] * 64 + lane];
            ax += v0.x;
            ay += v0.y;
        }
    }
    float inv = 1.0f / (float)max(hi - lo, 1);
    reinterpret_cast<float2*>(out)[(size_t)node * 64 + lane] = make_float2(ax * inv, ay * inv);
}

// ---------------------------------------------------------------------------
// MFMA GEMM: out[n] = h[n]@Ws + hn[n]@Wn + bavg (hn read from `out`, wave-local
// in-place overwrite). Wave = 16 nodes x 128 outs, 4 k-steps x 16 MFMA.
// ---------------------------------------------------------------------------
template <bool BF>
__global__ __launch_bounds__(256) void mfma_gemm_kernel(
    const float* __restrict__ h, const unsigned short* __restrict__ hb,
    float* __restrict__ out, const unsigned short* __restrict__ wpack,
    const float* __restrict__ bavg) {
    const int lane = threadIdx.x & 63;
    const int wid = threadIdx.x >> 6;
    const int node_base = blockIdx.x * 64 + wid * 16;
    const int row = node_base + (lane & 15);
    const int rowc = min(row, N_NODES - 1);
    const int khi = lane >> 4;

    f32x4 acc[8] = {};
    const unsigned short* wn_p = wpack + 16384;

#pragma unroll
    for (int ks = 0; ks < 4; ++ks) {
        const int k0 = ks * 32 + khi * 8;
        bf16x8 ha, na;
        if (BF) {
            ha = *reinterpret_cast<const bf16x8*>(hb + (size_t)rowc * DIM + k0);
        } else {
            const float4* hp = reinterpret_cast<const float4*>(h + (size_t)rowc * DIM + k0);
            float4 x = hp[0], y = hp[1];
            ha[0] = (short)f2bf(x.x); ha[1] = (short)f2bf(x.y);
            ha[2] = (short)f2bf(x.z); ha[3] = (short)f2bf(x.w);
            ha[4] = (short)f2bf(y.x); ha[5] = (short)f2bf(y.y);
            ha[6] = (short)f2bf(y.z); ha[7] = (short)f2bf(y.w);
        }
        const float4* np0 = reinterpret_cast<const float4*>(out + (size_t)rowc * DIM + k0);
        float4 u = np0[0], v = np0[1];
        na[0] = (short)f2bf(u.x); na[1] = (short)f2bf(u.y);
        na[2] = (short)f2bf(u.z); na[3] = (short)f2bf(u.w);
        na[4] = (short)f2bf(v.x); na[5] = (short)f2bf(v.y);
        na[6] = (short)f2bf(v.z); na[7] = (short)f2bf(v.w);

#pragma unroll
        for (int nt = 0; nt < 8; ++nt) {
            bf16x8 bs = *reinterpret_cast<const bf16x8*>(wpack + (size_t)(((nt * 4 + ks) * 64 + lane) * 8));
            acc[nt] = __builtin_amdgcn_mfma_f32_16x16x32_bf16(ha, bs, acc[nt], 0, 0, 0);
            bf16x8 bn = *reinterpret_cast<const bf16x8*>(wn_p + (size_t)(((nt * 4 + ks) * 64 + lane) * 8));
            acc[nt] = __builtin_amdgcn_mfma_f32_16x16x32_bf16(na, bn, acc[nt], 0, 0, 0);
        }
    }

    // C/D layout (verified m89): col = lane&15, row = (lane>>4)*4 + reg
    const int r0 = node_base + khi * 4;
#pragma unroll
    for (int nt = 0; nt < 8; ++nt) {
        int o = nt * 16 + (lane & 15);
        float bb = bavg[o];
#pragma unroll
        for (int r = 0; r < 4; ++r) {
            int nr = r0 + r;
            if (nr < N_NODES) out[(size_t)nr * DIM + o] = acc[nt][r] + bb;
        }
    }
}

extern "C" void kernel_launch(void* const* d_in, const int* in_sizes, int n_in,
                              void* d_out, int out_size, void* d_ws, size_t ws_size,
                              hipStream_t stream) {
    const float* h  = (const float*)d_in[0];
    const int* src  = (const int*)d_in[1];
    const int* dst  = (const int*)d_in[2];
    const float* Ws = (const float*)d_in[3];
    const float* Wn = (const float*)d_in[4];
    const float* b  = (const float*)d_in[5];
    float* out = (float*)d_out;

    char* ws = (char*)d_ws;
    int* bcnt   = (int*)(ws + B_BCNT);
    int* bbase  = (int*)(ws + B_BBASE);
    int* bcur   = (int*)(ws + B_BCUR);
    int* rowoff = (int*)(ws + B_ROWOFF);
    int* csr    = (int*)(ws + B_CSR);
    unsigned short* wpack = (unsigned short*)(ws + B_WPACK);
    float* bavg = (float*)(ws + B_BAVG);
    unsigned short* hb = (unsigned short*)(ws + B_HB);
    int* ebuf   = (int*)(ws + B_EBUF);  // aliases hb head; dead before h2bf16

    const bool bf = (ws_size >= NEED_BF16);

    hipMemsetAsync(bcnt, 0, 256 * sizeof(int), stream);

    prep_weights_kernel<<<64, 256, 0, stream>>>(Ws, Wn, b, wpack, bavg);
    bucket_hist_kernel<<<NBLK, 256, 0, stream>>>(dst, bcnt);
    bucket_scan_kernel<<<1, 256, 0, stream>>>(bcnt, bbase, bcur);
    bucket_scatter_kernel<<<NBLK, 256, 0, stream>>>(src, dst, bcur, ebuf);
    csr_build_kernel<<<NB, 256, 0, stream>>>(bcnt, bbase, ebuf, rowoff, csr);
    if (bf) h2bf16_kernel<<<(N_NODES * DIM / 8) / 256, 256, 0, stream>>>(h, hb);
    if (bf)
        gather_mean_kernel<true><<<N_NODES / 4, 256, 0, stream>>>(h, hb, rowoff, csr, out);
    else
        gather_mean_kernel<false><<<N_NODES / 4, 256, 0, stream>>>(h, hb, rowoff, csr, out);
    const int gemm_blocks = (N_NODES + 63) / 64;
    if (bf)
        mfma_gemm_kernel<true><<<gemm_blocks, 256, 0, stream>>>(h, hb, out, wpack, bavg);
    else
        mfma_gemm_kernel<false><<<gemm_blocks, 256, 0, stream>>>(h, hb, out, wpack, bavg);
}

// Round 6
// 197.500 us; speedup vs baseline: 14.6928x; 1.0257x over previous
//
#include <hip/hip_runtime.h>

#define N_NODES 100000
#define N_EDGES 1600000
#define DIM 128
#define NH 4

#define NPB 512                                   // nodes per coarse bucket
#define NB 196                                    // ceil(N_NODES / NPB)
#define BCHUNK 2048                               // edges per block (bucket passes)
#define BEPT 8                                    // BCHUNK / 256
#define NBLK ((N_EDGES + BCHUNK - 1) / BCHUNK)    // 782

typedef __attribute__((ext_vector_type(8))) short bf16x8;
typedef __attribute__((ext_vector_type(4))) float f32x4;
typedef __attribute__((ext_vector_type(8))) unsigned short u16x8;

// ws layout, BYTE offsets (16B-aligned where it matters):
//   bcnt   : [0, 1024)           int[256] coarse bucket counts
//   bbase  : [1024, 2048)        int[256] bucket bases (excl scan)
//   bcur   : [2048, 3072)        int[256] bucket fill cursors
//   rowoff : [4096, 405504)      int[100001] node-level CSR offsets
//   csr    : [405504, 6805504)   int[1.6M] src ids bucketed+sorted by dst
//   wpack  : [6805504, 6871040)  bf16 MFMA-packed Ws|Wn
//   bavg   : [6871040, 6871552)  f32[128]
//   hb     : [6871552, 32471552) bf16 copy of h (25.6MB)
//   ebuf   : aliases hb region   int[1.6M] packed (src<<9|dstlo); dead before h2bf16
#define B_BCNT   0u
#define B_BBASE  1024u
#define B_BCUR   2048u
#define B_ROWOFF 4096u
#define B_CSR    405504u
#define B_WPACK  6805504u
#define B_BAVG   6871040u
#define B_HB     6871552u
#define B_EBUF   6871552u
#define NEED_BF16 32869376ull

// branchless RTNE f32->bf16 (finite inputs; no NaN path)
__device__ inline unsigned short f2bf(float x) {
    union { float f; unsigned u; } v; v.f = x;
    unsigned r = v.u + 0x7fffu + ((v.u >> 16) & 1u);
    return (unsigned short)(r >> 16);
}

// ---------------------------------------------------------------------------
// Head-average weights (mean over heads commutes with einsum+mean), pack into
// MFMA B-frag order: frag(nt,ks), lane l: col=nt*16+(l&15), k=ks*32+(l>>4)*8+e.
// ---------------------------------------------------------------------------
__global__ __launch_bounds__(256) void prep_weights_kernel(
    const float* __restrict__ Ws, const float* __restrict__ Wn,
    const float* __restrict__ b, unsigned short* __restrict__ wpack,
    float* __restrict__ bavg) {
    int i = blockIdx.x * 256 + threadIdx.x;  // i = k*128 + o
    if (i < DIM * DIM) {
        float s = 0.f, n = 0.f;
#pragma unroll
        for (int hh = 0; hh < NH; ++hh) {
            s += Ws[hh * DIM * DIM + i];
            n += Wn[hh * DIM * DIM + i];
        }
        s *= 0.25f; n *= 0.25f;
        int k = i >> 7, o = i & 127;
        int nt = o >> 4, lanelo = o & 15;
        int ks = k >> 5, lanehi = (k & 31) >> 3, e = k & 7;
        int pos = (((nt * 4 + ks) * 64) + lanehi * 16 + lanelo) * 8 + e;
        wpack[pos] = f2bf(s);
        wpack[16384 + pos] = f2bf(n);
    }
    if (i < DIM) {
        float bb = 0.f;
#pragma unroll
        for (int hh = 0; hh < NH; ++hh) bb += b[hh * DIM + i];
        bavg[i] = 0.25f * bb;
    }
}

// ---------------------------------------------------------------------------
// h -> bf16 copy (halves gather read stream; direct MFMA A-frags)
// ---------------------------------------------------------------------------
__global__ __launch_bounds__(256) void h2bf16_kernel(const float* __restrict__ h,
                                                     unsigned short* __restrict__ hb) {
    int i = blockIdx.x * 256 + threadIdx.x;  // 8 elems/thread
    const float4* p = reinterpret_cast<const float4*>(h) + (size_t)i * 2;
    float4 a = p[0], c = p[1];
    u16x8 r;
    r[0] = f2bf(a.x); r[1] = f2bf(a.y); r[2] = f2bf(a.z); r[3] = f2bf(a.w);
    r[4] = f2bf(c.x); r[5] = f2bf(c.y); r[6] = f2bf(c.z); r[7] = f2bf(c.w);
    reinterpret_cast<u16x8*>(hb)[i] = r;
}

// ---------------------------------------------------------------------------
// P1a: coarse histogram (bucket = dst>>9) via LDS counters
// ---------------------------------------------------------------------------
__global__ __launch_bounds__(256) void bucket_hist_kernel(const int* __restrict__ dst,
                                                          int* __restrict__ bcnt) {
    __shared__ int lc[256];
    int t = threadIdx.x;
    lc[t] = 0;
    __syncthreads();
    int e0 = blockIdx.x * BCHUNK;
#pragma unroll
    for (int j = 0; j < BEPT; ++j) {
        int e = e0 + j * 256 + t;
        if (e < N_EDGES) atomicAdd(&lc[dst[e] >> 9], 1);
    }
    __syncthreads();
    if (lc[t]) atomicAdd(&bcnt[t], lc[t]);
}

// ---------------------------------------------------------------------------
// P1b: scan 256 bucket counts -> bases; init cursors
// ---------------------------------------------------------------------------
__global__ __launch_bounds__(256) void bucket_scan_kernel(const int* __restrict__ bcnt,
                                                          int* __restrict__ bbase,
                                                          int* __restrict__ bcur) {
    __shared__ int s[256];
    int t = threadIdx.x;
    int v = bcnt[t];
    s[t] = v;
    __syncthreads();
    for (int off = 1; off < 256; off <<= 1) {
        int add = (t >= off) ? s[t - off] : 0;
        __syncthreads();
        s[t] += add;
        __syncthreads();
    }
    int ex = s[t] - v;
    bbase[t] = ex;
    bcur[t] = ex;
}

// ---------------------------------------------------------------------------
// P1c: bucket the edges. Block stages 2048 packed edges in LDS, reserves one
// contiguous chunk per bucket (1 global atomic/bucket/block), appends runs.
// Packed word: (src<<9) | (dst & 511)  -- 17+9 = 26 bits.
// ---------------------------------------------------------------------------
__global__ __launch_bounds__(256) void bucket_scatter_kernel(const int* __restrict__ src,
                                                             const int* __restrict__ dst,
                                                             int* __restrict__ bcur,
                                                             int* __restrict__ ebuf) {
    __shared__ int stage[BCHUNK];
    __shared__ int lc[256], lbase[256], lpos[256];
    int t = threadIdx.x;
    lc[t] = 0;
    lpos[t] = 0;
    __syncthreads();
    int e0 = blockIdx.x * BCHUNK;
#pragma unroll
    for (int j = 0; j < BEPT; ++j) {
        int e = e0 + j * 256 + t;
        if (e < N_EDGES) {
            int d = dst[e];
            stage[j * 256 + t] = (src[e] << 9) | (d & (NPB - 1));
            atomicAdd(&lc[d >> 9], 1);
        }
    }
    __syncthreads();
    if (lc[t]) lbase[t] = atomicAdd(&bcur[t], lc[t]);
    __syncthreads();
#pragma unroll
    for (int j = 0; j < BEPT; ++j) {
        int e = e0 + j * 256 + t;
        if (e < N_EDGES) {
            int b = dst[e] >> 9;
            int o = atomicAdd(&lpos[b], 1);
            ebuf[lbase[b] + o] = stage[j * 256 + t];
        }
    }
}

// ---------------------------------------------------------------------------
// P2: one block per bucket. Local 512-slot hist + scan -> rowoff, then scatter
// src into csr within the bucket's contiguous (L2-resident) window.
// ---------------------------------------------------------------------------
__global__ __launch_bounds__(256) void csr_build_kernel(const int* __restrict__ bcnt,
                                                        const int* __restrict__ bbase,
                                                        const int* __restrict__ ebuf,
                                                        int* __restrict__ rowoff,
                                                        int* __restrict__ csr) {
    __shared__ int h[NPB], off[NPB], cur[NPB], ss[256];
    int b = blockIdx.x, t = threadIdx.x;
    int cnt = bcnt[b], base = bbase[b];
    h[t] = 0; h[t + 256] = 0;
    cur[t] = 0; cur[t + 256] = 0;
    __syncthreads();
    for (int i = t; i < cnt; i += 256) atomicAdd(&h[ebuf[base + i] & (NPB - 1)], 1);
    __syncthreads();
    int e0 = h[2 * t], e1 = h[2 * t + 1];
    ss[t] = e0 + e1;
    __syncthreads();
    for (int o = 1; o < 256; o <<= 1) {
        int add = (t >= o) ? ss[t - o] : 0;
        __syncthreads();
        ss[t] += add;
        __syncthreads();
    }
    int ex = ss[t] - (e0 + e1);
    off[2 * t] = ex;
    off[2 * t + 1] = ex + e0;
    __syncthreads();
    int n0 = b * NPB;
#pragma unroll
    for (int k = 0; k < 2; ++k) {
        int s2 = t + k * 256;
        int n = n0 + s2;
        if (n <= N_NODES) rowoff[n] = base + off[s2];
    }
    for (int i = t; i < cnt; i += 256) {
        int p = ebuf[base + i];
        int nl = p & (NPB - 1);
        int o = atomicAdd(&cur[nl], 1);
        csr[base + off[nl] + o] = p >> 9;
    }
}

// ---------------------------------------------------------------------------
// gather-mean: one wave per node; 4 edge-slots x 16 lanes, 16B per lane.
// Per 4 edges: 1 dwordx4 row-load + 1 csr load + ~18 VALU (vs 8 loads before).
// Cross-group __shfl_xor reduce; group 0 writes the fp32 row into `out`.
// ---------------------------------------------------------------------------
template <bool BF>
__global__ __launch_bounds__(256) void gather_mean_kernel(
    const float* __restrict__ h, const unsigned short* __restrict__ hb,
    const int* __restrict__ rowoff, const int* __restrict__ csr,
    float* __restrict__ out) {
    int node = blockIdx.x * 4 + (threadIdx.x >> 6);
    int lane = threadIdx.x & 63;
    int g = lane >> 4;   // edge slot
    int c = lane & 15;   // 16B chunk within row (8 elems)
    int lo = rowoff[node];
    int hi = rowoff[node + 1];
    float a0 = 0.f, a1 = 0.f, a2 = 0.f, a3 = 0.f;
    float a4 = 0.f, a5 = 0.f, a6 = 0.f, a7 = 0.f;
    if (BF) {
        for (int k = lo + g; k < hi; k += 4) {
            int s = csr[k];
            uint4 v = *reinterpret_cast<const uint4*>(hb + (size_t)s * DIM + c * 8);
            a0 += __uint_as_float(v.x << 16);
            a1 += __uint_as_float(v.x & 0xffff0000u);
            a2 += __uint_as_float(v.y << 16);
            a3 += __uint_as_float(v.y & 0xffff0000u);
            a4 += __uint_as_float(v.z << 16);
            a5 += __uint_as_float(v.z & 0xffff0000u);
            a6 += __uint_as_float(v.w << 16);
            a7 += __uint_as_float(v.w & 0xffff0000u);
        }
    } else {
        for (int k = lo + g; k < hi; k += 4) {
            int s = csr[k];
            const float4* p = reinterpret_cast<const float4*>(h + (size_t)s * DIM + c * 8);
            float4 x = p[0], y = p[1];
            a0 += x.x; a1 += x.y; a2 += x.z; a3 += x.w;
            a4 += y.x; a5 += y.y; a6 += y.z; a7 += y.w;
        }
    }
    // sum the 4 edge-slot groups (lanes l, l^16, l^32, l^48)
    a0 += __shfl_xor(a0, 16, 64); a0 += __shfl_xor(a0, 32, 64);
    a1 += __shfl_xor(a1, 16, 64); a1 += __shfl_xor(a1, 32, 64);
    a2 += __shfl_xor(a2, 16, 64); a2 += __shfl_xor(a2, 32, 64);
    a3 += __shfl_xor(a3, 16, 64); a3 += __shfl_xor(a3, 32, 64);
    a4 += __shfl_xor(a4, 16, 64); a4 += __shfl_xor(a4, 32, 64);
    a5 += __shfl_xor(a5, 16, 64); a5 += __shfl_xor(a5, 32, 64);
    a6 += __shfl_xor(a6, 16, 64); a6 += __shfl_xor(a6, 32, 64);
    a7 += __shfl_xor(a7, 16, 64); a7 += __shfl_xor(a7, 32, 64);
    float inv = 1.0f / (float)max(hi - lo, 1);
    if (g == 0) {
        float4 r0, r1;
        r0.x = a0 * inv; r0.y = a1 * inv; r0.z = a2 * inv; r0.w = a3 * inv;
        r1.x = a4 * inv; r1.y = a5 * inv; r1.z = a6 * inv; r1.w = a7 * inv;
        float4* q = reinterpret_cast<float4*>(out + (size_t)node * DIM + c * 8);
        q[0] = r0;
        q[1] = r1;
    }
}

// ---------------------------------------------------------------------------
// MFMA GEMM: out[n] = h[n]@Ws + hn[n]@Wn + bavg (hn read from `out`, wave-local
// in-place overwrite). Wave = 16 nodes x 128 outs, 4 k-steps x 16 MFMA.
// ---------------------------------------------------------------------------
template <bool BF>
__global__ __launch_bounds__(256) void mfma_gemm_kernel(
    const float* __restrict__ h, const unsigned short* __restrict__ hb,
    float* __restrict__ out, const unsigned short* __restrict__ wpack,
    const float* __restrict__ bavg) {
    const int lane = threadIdx.x & 63;
    const int wid = threadIdx.x >> 6;
    const int node_base = blockIdx.x * 64 + wid * 16;
    const int row = node_base + (lane & 15);
    const int rowc = min(row, N_NODES - 1);
    const int khi = lane >> 4;

    f32x4 acc[8] = {};
    const unsigned short* wn_p = wpack + 16384;

#pragma unroll
    for (int ks = 0; ks < 4; ++ks) {
        const int k0 = ks * 32 + khi * 8;
        bf16x8 ha, na;
        if (BF) {
            ha = *reinterpret_cast<const bf16x8*>(hb + (size_t)rowc * DIM + k0);
        } else {
            const float4* hp = reinterpret_cast<const float4*>(h + (size_t)rowc * DIM + k0);
            float4 x = hp[0], y = hp[1];
            ha[0] = (short)f2bf(x.x); ha[1] = (short)f2bf(x.y);
            ha[2] = (short)f2bf(x.z); ha[3] = (short)f2bf(x.w);
            ha[4] = (short)f2bf(y.x); ha[5] = (short)f2bf(y.y);
            ha[6] = (short)f2bf(y.z); ha[7] = (short)f2bf(y.w);
        }
        const float4* np0 = reinterpret_cast<const float4*>(out + (size_t)rowc * DIM + k0);
        float4 u = np0[0], v = np0[1];
        na[0] = (short)f2bf(u.x); na[1] = (short)f2bf(u.y);
        na[2] = (short)f2bf(u.z); na[3] = (short)f2bf(u.w);
        na[4] = (short)f2bf(v.x); na[5] = (short)f2bf(v.y);
        na[6] = (short)f2bf(v.z); na[7] = (short)f2bf(v.w);

#pragma unroll
        for (int nt = 0; nt < 8; ++nt) {
            bf16x8 bs = *reinterpret_cast<const bf16x8*>(wpack + (size_t)(((nt * 4 + ks) * 64 + lane) * 8));
            acc[nt] = __builtin_amdgcn_mfma_f32_16x16x32_bf16(ha, bs, acc[nt], 0, 0, 0);
            bf16x8 bn = *reinterpret_cast<const bf16x8*>(wn_p + (size_t)(((nt * 4 + ks) * 64 + lane) * 8));
            acc[nt] = __builtin_amdgcn_mfma_f32_16x16x32_bf16(na, bn, acc[nt], 0, 0, 0);
        }
    }

    // C/D layout (verified m89): col = lane&15, row = (lane>>4)*4 + reg
    const int r0 = node_base + khi * 4;
#pragma unroll
    for (int nt = 0; nt < 8; ++nt) {
        int o = nt * 16 + (lane & 15);
        float bb = bavg[o];
#pragma unroll
        for (int r = 0; r < 4; ++r) {
            int nr = r0 + r;
            if (nr < N_NODES) out[(size_t)nr * DIM + o] = acc[nt][r] + bb;
        }
    }
}

extern "C" void kernel_launch(void* const* d_in, const int* in_sizes, int n_in,
                              void* d_out, int out_size, void* d_ws, size_t ws_size,
                              hipStream_t stream) {
    const float* h  = (const float*)d_in[0];
    const int* src  = (const int*)d_in[1];
    const int* dst  = (const int*)d_in[2];
    const float* Ws = (const float*)d_in[3];
    const float* Wn = (const float*)d_in[4];
    const float* b  = (const float*)d_in[5];
    float* out = (float*)d_out;

    char* ws = (char*)d_ws;
    int* bcnt   = (int*)(ws + B_BCNT);
    int* bbase  = (int*)(ws + B_BBASE);
    int* bcur   = (int*)(ws + B_BCUR);
    int* rowoff = (int*)(ws + B_ROWOFF);
    int* csr    = (int*)(ws + B_CSR);
    unsigned short* wpack = (unsigned short*)(ws + B_WPACK);
    float* bavg = (float*)(ws + B_BAVG);
    unsigned short* hb = (unsigned short*)(ws + B_HB);
    int* ebuf   = (int*)(ws + B_EBUF);  // aliases hb head; dead before h2bf16

    const bool bf = (ws_size >= NEED_BF16);

    hipMemsetAsync(bcnt, 0, 256 * sizeof(int), stream);

    prep_weights_kernel<<<64, 256, 0, stream>>>(Ws, Wn, b, wpack, bavg);
    bucket_hist_kernel<<<NBLK, 256, 0, stream>>>(dst, bcnt);
    bucket_scan_kernel<<<1, 256, 0, stream>>>(bcnt, bbase, bcur);
    bucket_scatter_kernel<<<NBLK, 256, 0, stream>>>(src, dst, bcur, ebuf);
    csr_build_kernel<<<NB, 256, 0, stream>>>(bcnt, bbase, ebuf, rowoff, csr);
    if (bf) h2bf16_kernel<<<(N_NODES * DIM / 8) / 256, 256, 0, stream>>>(h, hb);
    if (bf)
        gather_mean_kernel<true><<<N_NODES / 4, 256, 0, stream>>>(h, hb, rowoff, csr, out);
    else
        gather_mean_kernel<false><<<N_NODES / 4, 256, 0, stream>>>(h, hb, rowoff, csr, out);
    const int gemm_blocks = (N_NODES + 63) / 64;
    if (bf)
        mfma_gemm_kernel<true><<<gemm_blocks, 256, 0, stream>>>(h, hb, out, wpack, bavg);
    else
        mfma_gemm_kernel<false><<<gemm_blocks, 256, 0, stream>>>(h, hb, out, wpack, bavg);
}

// Round 7
// 170.566 us; speedup vs baseline: 17.0130x; 1.1579x over previous
//
#include <hip/hip_runtime.h>

#define N_NODES 100000
#define N_EDGES 1600000
#define DIM 128
#define NH 4

#define NPB 512                                   // nodes per coarse bucket
#define NB 196                                    // ceil(N_NODES / NPB)
#define BCHUNK 8192                               // edges per block (bucket passes)
#define BEPT 32                                   // BCHUNK / 256
#define NBLK ((N_EDGES + BCHUNK - 1) / BCHUNK)    // 196

typedef __attribute__((ext_vector_type(8))) short bf16x8;
typedef __attribute__((ext_vector_type(4))) float f32x4;
typedef __attribute__((ext_vector_type(8))) unsigned short u16x8;

// ws layout, BYTE offsets (16B-aligned where it matters):
//   bcnt   : [0, 1024)           int[256] coarse bucket counts
//   bbase  : [1024, 2048)        int[256] bucket bases (excl scan)
//   bcur   : [2048, 3072)        int[256] bucket fill cursors
//   rowoff : [4096, 405504)      int[100001] node-level CSR offsets
//   csr    : [405504, 6805504)   int[1.6M] src ids bucketed+sorted by dst
//   wpack  : [6805504, 6871040)  bf16 MFMA-packed Ws|Wn
//   bavg   : [6871040, 6871552)  f32[128]
//   hb     : [6871552, 32471552) bf16 copy of h (25.6MB)
//   ebuf   : aliases hb region   int[1.6M] packed (src<<9|dstlo); dead before h2bf16
#define B_BCNT   0u
#define B_BBASE  1024u
#define B_BCUR   2048u
#define B_ROWOFF 4096u
#define B_CSR    405504u
#define B_WPACK  6805504u
#define B_BAVG   6871040u
#define B_HB     6871552u
#define B_EBUF   6871552u
#define NEED_BF16 32869376ull

// branchless RTNE f32->bf16 (finite inputs; no NaN path)
__device__ inline unsigned short f2bf(float x) {
    union { float f; unsigned u; } v; v.f = x;
    unsigned r = v.u + 0x7fffu + ((v.u >> 16) & 1u);
    return (unsigned short)(r >> 16);
}

// ---------------------------------------------------------------------------
// Head-average weights (mean over heads commutes with einsum+mean), pack into
// MFMA B-frag order. Block 0 also zeroes bcnt (replaces a memset dispatch).
// ---------------------------------------------------------------------------
__global__ __launch_bounds__(256) void prep_weights_kernel(
    const float* __restrict__ Ws, const float* __restrict__ Wn,
    const float* __restrict__ b, unsigned short* __restrict__ wpack,
    float* __restrict__ bavg, int* __restrict__ bcnt) {
    if (blockIdx.x == 0) bcnt[threadIdx.x] = 0;
    int i = blockIdx.x * 256 + threadIdx.x;  // i = k*128 + o
    if (i < DIM * DIM) {
        float s = 0.f, n = 0.f;
#pragma unroll
        for (int hh = 0; hh < NH; ++hh) {
            s += Ws[hh * DIM * DIM + i];
            n += Wn[hh * DIM * DIM + i];
        }
        s *= 0.25f; n *= 0.25f;
        int k = i >> 7, o = i & 127;
        int nt = o >> 4, lanelo = o & 15;
        int ks = k >> 5, lanehi = (k & 31) >> 3, e = k & 7;
        int pos = (((nt * 4 + ks) * 64) + lanehi * 16 + lanelo) * 8 + e;
        wpack[pos] = f2bf(s);
        wpack[16384 + pos] = f2bf(n);
    }
    if (i < DIM) {
        float bb = 0.f;
#pragma unroll
        for (int hh = 0; hh < NH; ++hh) bb += b[hh * DIM + i];
        bavg[i] = 0.25f * bb;
    }
}

// ---------------------------------------------------------------------------
// h -> bf16 copy (halves gather read stream; direct MFMA A-frags)
// ---------------------------------------------------------------------------
__global__ __launch_bounds__(256) void h2bf16_kernel(const float* __restrict__ h,
                                                     unsigned short* __restrict__ hb) {
    int i = blockIdx.x * 256 + threadIdx.x;  // 8 elems/thread
    const float4* p = reinterpret_cast<const float4*>(h) + (size_t)i * 2;
    float4 a = p[0], c = p[1];
    u16x8 r;
    r[0] = f2bf(a.x); r[1] = f2bf(a.y); r[2] = f2bf(a.z); r[3] = f2bf(a.w);
    r[4] = f2bf(c.x); r[5] = f2bf(c.y); r[6] = f2bf(c.z); r[7] = f2bf(c.w);
    reinterpret_cast<u16x8*>(hb)[i] = r;
}

// ---------------------------------------------------------------------------
// P1a: coarse histogram (bucket = dst>>9) via LDS counters
// ---------------------------------------------------------------------------
__global__ __launch_bounds__(256) void bucket_hist_kernel(const int* __restrict__ dst,
                                                          int* __restrict__ bcnt) {
    __shared__ int lc[256];
    int t = threadIdx.x;
    lc[t] = 0;
    __syncthreads();
    int e0 = blockIdx.x * BCHUNK;
#pragma unroll 4
    for (int j = 0; j < BEPT; ++j) {
        int e = e0 + j * 256 + t;
        if (e < N_EDGES) atomicAdd(&lc[dst[e] >> 9], 1);
    }
    __syncthreads();
    if (lc[t]) atomicAdd(&bcnt[t], lc[t]);
}

// ---------------------------------------------------------------------------
// P1b: scan 256 bucket counts -> bases; init cursors
// ---------------------------------------------------------------------------
__global__ __launch_bounds__(256) void bucket_scan_kernel(const int* __restrict__ bcnt,
                                                          int* __restrict__ bbase,
                                                          int* __restrict__ bcur) {
    __shared__ int s[256];
    int t = threadIdx.x;
    int v = bcnt[t];
    s[t] = v;
    __syncthreads();
    for (int off = 1; off < 256; off <<= 1) {
        int add = (t >= off) ? s[t - off] : 0;
        __syncthreads();
        s[t] += add;
        __syncthreads();
    }
    int ex = s[t] - v;
    bbase[t] = ex;
    bcur[t] = ex;
}

// ---------------------------------------------------------------------------
// P1c: bucket the edges. Block stages 8192 packed edges in LDS, reserves one
// contiguous chunk per bucket (1 global atomic/bucket/block), appends ~32-edge
// (128B, full-cacheline) runs. Packed word: (src<<9) | (dst & 511).
// ---------------------------------------------------------------------------
__global__ __launch_bounds__(256) void bucket_scatter_kernel(const int* __restrict__ src,
                                                             const int* __restrict__ dst,
                                                             int* __restrict__ bcur,
                                                             int* __restrict__ ebuf) {
    __shared__ int stage[BCHUNK];
    __shared__ int lc[256], lbase[256], lpos[256];
    int t = threadIdx.x;
    lc[t] = 0;
    lpos[t] = 0;
    __syncthreads();
    int e0 = blockIdx.x * BCHUNK;
#pragma unroll 4
    for (int j = 0; j < BEPT; ++j) {
        int e = e0 + j * 256 + t;
        if (e < N_EDGES) {
            int d = dst[e];
            stage[j * 256 + t] = (src[e] << 9) | (d & (NPB - 1));
            atomicAdd(&lc[d >> 9], 1);
        }
    }
    __syncthreads();
    if (lc[t]) lbase[t] = atomicAdd(&bcur[t], lc[t]);
    __syncthreads();
#pragma unroll 4
    for (int j = 0; j < BEPT; ++j) {
        int e = e0 + j * 256 + t;
        if (e < N_EDGES) {
            int b = dst[e] >> 9;
            int o = atomicAdd(&lpos[b], 1);
            ebuf[lbase[b] + o] = stage[j * 256 + t];
        }
    }
}

// ---------------------------------------------------------------------------
// P2: one block per bucket. Local 512-slot hist + scan -> rowoff, then scatter
// src into csr within the bucket's contiguous (L2-resident) window.
// ---------------------------------------------------------------------------
__global__ __launch_bounds__(256) void csr_build_kernel(const int* __restrict__ bcnt,
                                                        const int* __restrict__ bbase,
                                                        const int* __restrict__ ebuf,
                                                        int* __restrict__ rowoff,
                                                        int* __restrict__ csr) {
    __shared__ int h[NPB], off[NPB], cur[NPB], ss[256];
    int b = blockIdx.x, t = threadIdx.x;
    int cnt = bcnt[b], base = bbase[b];
    h[t] = 0; h[t + 256] = 0;
    cur[t] = 0; cur[t + 256] = 0;
    __syncthreads();
    for (int i = t; i < cnt; i += 256) atomicAdd(&h[ebuf[base + i] & (NPB - 1)], 1);
    __syncthreads();
    int e0 = h[2 * t], e1 = h[2 * t + 1];
    ss[t] = e0 + e1;
    __syncthreads();
    for (int o = 1; o < 256; o <<= 1) {
        int add = (t >= o) ? ss[t - o] : 0;
        __syncthreads();
        ss[t] += add;
        __syncthreads();
    }
    int ex = ss[t] - (e0 + e1);
    off[2 * t] = ex;
    off[2 * t + 1] = ex + e0;
    __syncthreads();
    int n0 = b * NPB;
#pragma unroll
    for (int k = 0; k < 2; ++k) {
        int s2 = t + k * 256;
        int n = n0 + s2;
        if (n <= N_NODES) rowoff[n] = base + off[s2];
    }
    for (int i = t; i < cnt; i += 256) {
        int p = ebuf[base + i];
        int nl = p & (NPB - 1);
        int o = atomicAdd(&cur[nl], 1);
        csr[base + off[nl] + o] = p >> 9;
    }
}

// ---------------------------------------------------------------------------
// gather-mean: one wave per node; 4 edge-slots x 16 lanes, 16B per lane,
// 2 independent row loads in flight per slot. BF path stores the mean row as
// packed bf16 in the FIRST HALF of the node's out row (same rounding point as
// the GEMM's old f2bf -> bitwise-identical final output), halving handoff IO.
// ---------------------------------------------------------------------------
template <bool BF>
__global__ __launch_bounds__(256) void gather_mean_kernel(
    const float* __restrict__ h, const unsigned short* __restrict__ hb,
    const int* __restrict__ rowoff, const int* __restrict__ csr,
    float* __restrict__ out) {
    int node = blockIdx.x * 4 + (threadIdx.x >> 6);
    int lane = threadIdx.x & 63;
    int g = lane >> 4;   // edge slot
    int c = lane & 15;   // 16B chunk within row (8 elems)
    int lo = rowoff[node];
    int hi = rowoff[node + 1];
    float a0 = 0.f, a1 = 0.f, a2 = 0.f, a3 = 0.f;
    float a4 = 0.f, a5 = 0.f, a6 = 0.f, a7 = 0.f;
    if (BF) {
        int k = lo + g;
        for (; k + 4 < hi; k += 8) {  // 2 independent row loads in flight
            int s0 = csr[k], s1 = csr[k + 4];
            uint4 v = *reinterpret_cast<const uint4*>(hb + (size_t)s0 * DIM + c * 8);
            uint4 w = *reinterpret_cast<const uint4*>(hb + (size_t)s1 * DIM + c * 8);
            a0 += __uint_as_float(v.x << 16) + __uint_as_float(w.x << 16);
            a1 += __uint_as_float(v.x & 0xffff0000u) + __uint_as_float(w.x & 0xffff0000u);
            a2 += __uint_as_float(v.y << 16) + __uint_as_float(w.y << 16);
            a3 += __uint_as_float(v.y & 0xffff0000u) + __uint_as_float(w.y & 0xffff0000u);
            a4 += __uint_as_float(v.z << 16) + __uint_as_float(w.z << 16);
            a5 += __uint_as_float(v.z & 0xffff0000u) + __uint_as_float(w.z & 0xffff0000u);
            a6 += __uint_as_float(v.w << 16) + __uint_as_float(w.w << 16);
            a7 += __uint_as_float(v.w & 0xffff0000u) + __uint_as_float(w.w & 0xffff0000u);
        }
        if (k < hi) {
            uint4 v = *reinterpret_cast<const uint4*>(hb + (size_t)csr[k] * DIM + c * 8);
            a0 += __uint_as_float(v.x << 16);
            a1 += __uint_as_float(v.x & 0xffff0000u);
            a2 += __uint_as_float(v.y << 16);
            a3 += __uint_as_float(v.y & 0xffff0000u);
            a4 += __uint_as_float(v.z << 16);
            a5 += __uint_as_float(v.z & 0xffff0000u);
            a6 += __uint_as_float(v.w << 16);
            a7 += __uint_as_float(v.w & 0xffff0000u);
        }
    } else {
        for (int k = lo + g; k < hi; k += 4) {
            int s = csr[k];
            const float4* p = reinterpret_cast<const float4*>(h + (size_t)s * DIM + c * 8);
            float4 x = p[0], y = p[1];
            a0 += x.x; a1 += x.y; a2 += x.z; a3 += x.w;
            a4 += y.x; a5 += y.y; a6 += y.z; a7 += y.w;
        }
    }
    // sum the 4 edge-slot groups (lanes l, l^16, l^32, l^48)
    a0 += __shfl_xor(a0, 16, 64); a0 += __shfl_xor(a0, 32, 64);
    a1 += __shfl_xor(a1, 16, 64); a1 += __shfl_xor(a1, 32, 64);
    a2 += __shfl_xor(a2, 16, 64); a2 += __shfl_xor(a2, 32, 64);
    a3 += __shfl_xor(a3, 16, 64); a3 += __shfl_xor(a3, 32, 64);
    a4 += __shfl_xor(a4, 16, 64); a4 += __shfl_xor(a4, 32, 64);
    a5 += __shfl_xor(a5, 16, 64); a5 += __shfl_xor(a5, 32, 64);
    a6 += __shfl_xor(a6, 16, 64); a6 += __shfl_xor(a6, 32, 64);
    a7 += __shfl_xor(a7, 16, 64); a7 += __shfl_xor(a7, 32, 64);
    float inv = 1.0f / (float)max(hi - lo, 1);
    if (g == 0) {
        if (BF) {
            u16x8 r;
            r[0] = f2bf(a0 * inv); r[1] = f2bf(a1 * inv);
            r[2] = f2bf(a2 * inv); r[3] = f2bf(a3 * inv);
            r[4] = f2bf(a4 * inv); r[5] = f2bf(a5 * inv);
            r[6] = f2bf(a6 * inv); r[7] = f2bf(a7 * inv);
            // packed bf16 hn in the first half of the node's out row
            *reinterpret_cast<u16x8*>(reinterpret_cast<unsigned short*>(out) +
                                      (size_t)node * 256 + c * 8) = r;
        } else {
            float4 r0, r1;
            r0.x = a0 * inv; r0.y = a1 * inv; r0.z = a2 * inv; r0.w = a3 * inv;
            r1.x = a4 * inv; r1.y = a5 * inv; r1.z = a6 * inv; r1.w = a7 * inv;
            float4* q = reinterpret_cast<float4*>(out + (size_t)node * DIM + c * 8);
            q[0] = r0;
            q[1] = r1;
        }
    }
}

// ---------------------------------------------------------------------------
// MFMA GEMM: out[n] = h[n]@Ws + hn[n]@Wn + bavg. BF path: hn is packed bf16 in
// the first half of each out row (wave-local in-place overwrite). Wave = 16
// nodes x 128 outs, 4 k-steps x 16 MFMA.
// ---------------------------------------------------------------------------
template <bool BF>
__global__ __launch_bounds__(256) void mfma_gemm_kernel(
    const float* __restrict__ h, const unsigned short* __restrict__ hb,
    float* __restrict__ out, const unsigned short* __restrict__ wpack,
    const float* __restrict__ bavg) {
    const int lane = threadIdx.x & 63;
    const int wid = threadIdx.x >> 6;
    const int node_base = blockIdx.x * 64 + wid * 16;
    const int row = node_base + (lane & 15);
    const int rowc = min(row, N_NODES - 1);
    const int khi = lane >> 4;

    f32x4 acc[8] = {};
    const unsigned short* wn_p = wpack + 16384;

#pragma unroll
    for (int ks = 0; ks < 4; ++ks) {
        const int k0 = ks * 32 + khi * 8;
        bf16x8 ha, na;
        if (BF) {
            ha = *reinterpret_cast<const bf16x8*>(hb + (size_t)rowc * DIM + k0);
            na = *reinterpret_cast<const bf16x8*>(
                reinterpret_cast<const unsigned short*>(out) + (size_t)rowc * 256 + k0);
        } else {
            const float4* hp = reinterpret_cast<const float4*>(h + (size_t)rowc * DIM + k0);
            float4 x = hp[0], y = hp[1];
            ha[0] = (short)f2bf(x.x); ha[1] = (short)f2bf(x.y);
            ha[2] = (short)f2bf(x.z); ha[3] = (short)f2bf(x.w);
            ha[4] = (short)f2bf(y.x); ha[5] = (short)f2bf(y.y);
            ha[6] = (short)f2bf(y.z); ha[7] = (short)f2bf(y.w);
            const float4* np0 = reinterpret_cast<const float4*>(out + (size_t)rowc * DIM + k0);
            float4 u = np0[0], v = np0[1];
            na[0] = (short)f2bf(u.x); na[1] = (short)f2bf(u.y);
            na[2] = (short)f2bf(u.z); na[3] = (short)f2bf(u.w);
            na[4] = (short)f2bf(v.x); na[5] = (short)f2bf(v.y);
            na[6] = (short)f2bf(v.z); na[7] = (short)f2bf(v.w);
        }

#pragma unroll
        for (int nt = 0; nt < 8; ++nt) {
            bf16x8 bs = *reinterpret_cast<const bf16x8*>(wpack + (size_t)(((nt * 4 + ks) * 64 + lane) * 8));
            acc[nt] = __builtin_amdgcn_mfma_f32_16x16x32_bf16(ha, bs, acc[nt], 0, 0, 0);
            bf16x8 bn = *reinterpret_cast<const bf16x8*>(wn_p + (size_t)(((nt * 4 + ks) * 64 + lane) * 8));
            acc[nt] = __builtin_amdgcn_mfma_f32_16x16x32_bf16(na, bn, acc[nt], 0, 0, 0);
        }
    }

    // C/D layout (verified m89): col = lane&15, row = (lane>>4)*4 + reg
    const int r0 = node_base + khi * 4;
#pragma unroll
    for (int nt = 0; nt < 8; ++nt) {
        int o = nt * 16 + (lane & 15);
        float bb = bavg[o];
#pragma unroll
        for (int r = 0; r < 4; ++r) {
            int nr = r0 + r;
            if (nr < N_NODES) out[(size_t)nr * DIM + o] = acc[nt][r] + bb;
        }
    }
}

extern "C" void kernel_launch(void* const* d_in, const int* in_sizes, int n_in,
                              void* d_out, int out_size, void* d_ws, size_t ws_size,
                              hipStream_t stream) {
    const float* h  = (const float*)d_in[0];
    const int* src  = (const int*)d_in[1];
    const int* dst  = (const int*)d_in[2];
    const float* Ws = (const float*)d_in[3];
    const float* Wn = (const float*)d_in[4];
    const float* b  = (const float*)d_in[5];
    float* out = (float*)d_out;

    char* ws = (char*)d_ws;
    int* bcnt   = (int*)(ws + B_BCNT);
    int* bbase  = (int*)(ws + B_BBASE);
    int* bcur   = (int*)(ws + B_BCUR);
    int* rowoff = (int*)(ws + B_ROWOFF);
    int* csr    = (int*)(ws + B_CSR);
    unsigned short* wpack = (unsigned short*)(ws + B_WPACK);
    float* bavg = (float*)(ws + B_BAVG);
    unsigned short* hb = (unsigned short*)(ws + B_HB);
    int* ebuf   = (int*)(ws + B_EBUF);  // aliases hb head; dead before h2bf16

    const bool bf = (ws_size >= NEED_BF16);

    prep_weights_kernel<<<64, 256, 0, stream>>>(Ws, Wn, b, wpack, bavg, bcnt);
    bucket_hist_kernel<<<NBLK, 256, 0, stream>>>(dst, bcnt);
    bucket_scan_kernel<<<1, 256, 0, stream>>>(bcnt, bbase, bcur);
    bucket_scatter_kernel<<<NBLK, 256, 0, stream>>>(src, dst, bcur, ebuf);
    csr_build_kernel<<<NB, 256, 0, stream>>>(bcnt, bbase, ebuf, rowoff, csr);
    if (bf) h2bf16_kernel<<<(N_NODES * DIM / 8) / 256, 256, 0, stream>>>(h, hb);
    if (bf)
        gather_mean_kernel<true><<<N_NODES / 4, 256, 0, stream>>>(h, hb, rowoff, csr, out);
    else
        gather_mean_kernel<false><<<N_NODES / 4, 256, 0, stream>>>(h, hb, rowoff, csr, out);
    const int gemm_blocks = (N_NODES + 63) / 64;
    if (bf)
        mfma_gemm_kernel<true><<<gemm_blocks, 256, 0, stream>>>(h, hb, out, wpack, bavg);
    else
        mfma_gemm_kernel<false><<<gemm_blocks, 256, 0, stream>>>(h, hb, out, wpack, bavg);
}